// Round 9
// baseline (2467.050 us; speedup 1.0000x reference)
//
#include <hip/hip_runtime.h>
#include <hip/hip_bf16.h>
#include <math.h>

#define HFEAT 75
#define WFEAT 120
#define NPIX (HFEAT*WFEAT)      // 9000
#define NANCH 81000
#define PRE 6000
#define POST 300
#define SUPW 94                 // ceil(6000/64)
#define HBITS 18
#define HBUCK (1<<HBITS)        // 262144
#define HCHUNK (HBUCK/1024)     // 256

typedef __attribute__((ext_vector_type(4))) float f32x4;
typedef __attribute__((ext_vector_type(8))) short short8;   // 8 bf16 (4 VGPRs)

// 9 base anchors (base_size=16, ratios .5/1/2, scales 8/16/32), precomputed
// exactly per the numpy reference (incl. banker's rounding of 11.5 -> 12).
__constant__ float ANCH[9][4] = {
  {-84.f,-40.f,99.f,55.f},  {-176.f,-88.f,191.f,103.f},{-360.f,-184.f,375.f,199.f},
  {-56.f,-56.f,71.f,71.f},  {-120.f,-120.f,135.f,135.f},{-248.f,-248.f,263.f,263.f},
  {-36.f,-80.f,51.f,95.f},  {-80.f,-168.f,95.f,183.f}, {-168.f,-344.f,183.f,359.f}};

// fp32 -> 3x bf16 split: a ~= s1+s2+s3 (~26 mantissa bits)
__device__ inline void split3(float a, short& s1, short& s2, short& s3) {
  __hip_bfloat16 b1 = __float2bfloat16(a);
  float r = a - __bfloat162float(b1);
  __hip_bfloat16 b2 = __float2bfloat16(r);
  float r2 = r - __bfloat162float(b2);
  __hip_bfloat16 b3 = __float2bfloat16(r2);
  s1 = __builtin_bit_cast(short, b1);
  s2 = __builtin_bit_cast(short, b2);
  s3 = __builtin_bit_cast(short, b3);
}

// ---------------- conv 3x3 + bias + relu via bf16x3 MFMA ----------------
// Implicit GEMM: M=64px (row chunk), N=64oc, K=4608 (16 ic-chunks x 9 taps).
// 6 MFMA products per k-step approximate fp32 (dropped terms ~2^-26).
// grid (75 y, 2 xhalf, 8 ocb); 4 waves: (wm,wn) in 2x2, each 32px x 32oc.
__global__ __launch_bounds__(256) void conv3_mfma(
    const float* __restrict__ in, const float* __restrict__ w,
    const float* __restrict__ bias, float* __restrict__ out)
{
  __shared__ __align__(16) short in_b[3][3][66][40];  // [split][dy][col][icpad]
  __shared__ __align__(16) short w_b[3][64][40];      // [split][oc][icpad]
  const int tid = threadIdx.x;
  const int lane = tid & 63, wv = tid >> 6;
  const int wm = wv >> 1, wn = wv & 1;
  const int fr = lane & 15, fq = lane >> 4;
  const int y = blockIdx.x;
  const int x0 = blockIdx.y * 56;          // 0 or 56 (overlap recomputed identically)
  const int ocb = blockIdx.z * 64;

  f32x4 acc[2][2] = {};

  for (int c0 = 0; c0 < 512; c0 += 32) {
    __syncthreads();
    // stage + split input halo: 32ic x 3dy x 66cols
    for (int i = tid; i < 32*3*66; i += 256) {
      int ic = i / 198, r = i - ic * 198;
      int dy = r / 66, cc = r - dy * 66;
      int gy = y + dy - 1, gx = x0 - 1 + cc;
      float v = 0.f;
      if ((unsigned)gy < 75u && (unsigned)gx < 120u)
        v = in[(c0 + ic) * NPIX + gy * WFEAT + gx];
      short s1, s2, s3; split3(v, s1, s2, s3);
      in_b[0][dy][cc][ic] = s1; in_b[1][dy][cc][ic] = s2; in_b[2][dy][cc][ic] = s3;
    }
    for (int t = 0; t < 9; ++t) {
      __syncthreads();   // prev-tap w_b readers done (and in_b ready at t=0)
      for (int i = tid; i < 64*32; i += 256) {
        int oc = i >> 5, ic = i & 31;
        float v = w[(size_t)(ocb + oc) * 4608 + (c0 + ic) * 9 + t];
        short s1, s2, s3; split3(v, s1, s2, s3);
        w_b[0][oc][ic] = s1; w_b[1][oc][ic] = s2; w_b[2][oc][ic] = s3;
      }
      __syncthreads();
      const int dy = t / 3, dx = t - dy * 3;
      short8 af[3][2], bfr[3][2];
      #pragma unroll
      for (int m = 0; m < 2; ++m) {
        int col = wm * 32 + m * 16 + fr + dx;
        #pragma unroll
        for (int s = 0; s < 3; ++s)
          af[s][m] = *(const short8*)&in_b[s][dy][col][fq * 8];
      }
      #pragma unroll
      for (int n = 0; n < 2; ++n) {
        int oc = wn * 32 + n * 16 + fr;
        #pragma unroll
        for (int s = 0; s < 3; ++s)
          bfr[s][n] = *(const short8*)&w_b[s][oc][fq * 8];
      }
      const int pa[6] = {2, 0, 1, 1, 0, 0};
      const int pb[6] = {0, 2, 1, 0, 1, 0};
      #pragma unroll
      for (int p = 0; p < 6; ++p)
        #pragma unroll
        for (int m = 0; m < 2; ++m)
          #pragma unroll
          for (int n = 0; n < 2; ++n)
            acc[m][n] = __builtin_amdgcn_mfma_f32_16x16x32_bf16(
                af[pa[p]][m], bfr[pb[p]][n], acc[m][n], 0, 0, 0);
    }
  }

  #pragma unroll
  for (int n = 0; n < 2; ++n) {
    int oc = ocb + wn * 32 + n * 16 + fr;
    float bv = bias[oc];
    #pragma unroll
    for (int m = 0; m < 2; ++m) {
      #pragma unroll
      for (int r = 0; r < 4; ++r) {
        int px = wm * 32 + m * 16 + fq * 4 + r;
        float v = acc[m][n][r] + bv;
        out[(size_t)oc * NPIX + y * WFEAT + x0 + px] = v > 0.f ? v : 0.f;
      }
    }
  }
}

// ---------------- 1x1 convs: 18 cls + 36 bbox channels ----------------
__global__ __launch_bounds__(256) void conv1x1(
    const float* __restrict__ rpn,
    const float* __restrict__ wc, const float* __restrict__ bc,
    const float* __restrict__ wb, const float* __restrict__ bb,
    float* __restrict__ cls, float* __restrict__ bbox)
{
  __shared__ float r_s[64][128];
  __shared__ float w_s[54][64];
  const int tid = threadIdx.x;
  const int px0 = blockIdx.x * 128;
  const int px = tid & 127, g = tid >> 7;
  float tot[27];
  #pragma unroll
  for (int j = 0; j < 27; ++j) tot[j] = 0.f;
  for (int ic0 = 0; ic0 < 512; ic0 += 64) {
    __syncthreads();
    for (int i = tid; i < 64*128; i += 256) {
      int ic = i >> 7, p = i & 127;
      int gp = px0 + p;
      r_s[ic][p] = (gp < NPIX) ? rpn[(ic0 + ic) * NPIX + gp] : 0.f;
    }
    for (int i = tid; i < 54*64; i += 256) {
      int c = i >> 6, ic = i & 63;
      w_s[c][ic] = (c < 18) ? wc[c * 512 + ic0 + ic] : wb[(c - 18) * 512 + ic0 + ic];
    }
    __syncthreads();
    float acc[27];
    #pragma unroll
    for (int j = 0; j < 27; ++j) acc[j] = 0.f;
    for (int ic = 0; ic < 64; ++ic) {
      float iv = r_s[ic][px];
      #pragma unroll
      for (int j = 0; j < 27; ++j) acc[j] += iv * w_s[g * 27 + j][ic];
    }
    #pragma unroll
    for (int j = 0; j < 27; ++j) tot[j] += acc[j];
  }
  int gp = px0 + px;
  if (gp < NPIX) {
    for (int j = 0; j < 27; ++j) {
      int c = g * 27 + j;
      if (c < 18) cls[c * NPIX + gp] = tot[j] + bc[c];
      else        bbox[(c - 18) * NPIX + gp] = tot[j] + bb[c - 18];
    }
  }
}

// ---------------- score keys + box decode ----------------
__device__ inline unsigned long long dkey(double d) {
  long long b = __double_as_longlong(d);
  unsigned long long u = (unsigned long long)b;
  return (b < 0) ? ~u : (u | 0x8000000000000000ull);
}

__global__ void decode_score(
    const float* __restrict__ cls, const float* __restrict__ bbox,
    float* __restrict__ props, unsigned long long* __restrict__ keys)
{
  int i = blockIdx.x * 256 + threadIdx.x;
  if (i >= NANCH) return;
  int a = i % 9, p = i / 9;
  int x = p % WFEAT, y = p / WFEAT;
  float c0 = cls[a * NPIX + p], c1 = cls[(9 + a) * NPIX + p];
  double d = (double)c1 - (double)c0;
  unsigned long long s = dkey(d);
  keys[i] = (s & ~0x1FFFFull) | (unsigned long long)(0x1FFFFu - (unsigned)i);

  double ax1 = (double)ANCH[a][0] + 16.0 * x;
  double ay1 = (double)ANCH[a][1] + 16.0 * y;
  double ax2 = (double)ANCH[a][2] + 16.0 * x;
  double ay2 = (double)ANCH[a][3] + 16.0 * y;
  double aw = ax2 - ax1 + 1.0, ah = ay2 - ay1 + 1.0;
  double cx = ax1 + 0.5 * aw,  cy = ay1 + 0.5 * ah;
  double d0 = (double)bbox[(4*a+0) * NPIX + p];
  double d1 = (double)bbox[(4*a+1) * NPIX + p];
  double d2 = (double)bbox[(4*a+2) * NPIX + p];
  double d3 = (double)bbox[(4*a+3) * NPIX + p];
  double pcx = d0 * aw + cx, pcy = d1 * ah + cy;
  double pw = exp(d2) * aw,  ph = exp(d3) * ah;
  double bx1 = pcx - 0.5 * pw, by1 = pcy - 0.5 * ph;
  double bx2 = pcx + 0.5 * pw, by2 = pcy + 0.5 * ph;
  bx1 = fmin(fmax(bx1, 0.0), 1919.0); by1 = fmin(fmax(by1, 0.0), 1199.0);
  bx2 = fmin(fmax(bx2, 0.0), 1919.0); by2 = fmin(fmax(by2, 0.0), 1199.0);
  props[i*4+0] = (float)bx1; props[i*4+1] = (float)by1;
  props[i*4+2] = (float)bx2; props[i*4+3] = (float)by2;
}

// ---------------- exact top-6000 select --------------------------------
__global__ void hist_hi(const unsigned long long* __restrict__ keys,
                        unsigned* __restrict__ hist)
{
  int i = blockIdx.x * 256 + threadIdx.x;
  if (i < NANCH) atomicAdd(&hist[(unsigned)(keys[i] >> 46)], 1u);
}

__global__ __launch_bounds__(1024) void select_thresh(
    const unsigned long long* __restrict__ keys,
    const unsigned* __restrict__ hist, unsigned long long* __restrict__ thresh)
{
  __shared__ unsigned csum[1024];
  __shared__ int sh_bucket, sh_rank, sh_cnt;
  __shared__ unsigned long long buf[4096];
  const int tid = threadIdx.x;
  unsigned s = 0;
  for (int i = 0; i < HCHUNK; ++i) s += hist[tid * HCHUNK + i];
  csum[tid] = s;
  __syncthreads();
  if (tid == 0) {
    unsigned cum = 0; int tc = 0;
    for (int t = 1023; t >= 0; --t) {
      if (cum + csum[t] >= PRE) { tc = t; break; }
      cum += csum[t];
    }
    int B = tc * HCHUNK;
    for (int b0 = HCHUNK - 1; b0 >= 0; --b0) {
      unsigned h = hist[tc * HCHUNK + b0];
      if (cum + h >= PRE) { B = tc * HCHUNK + b0; break; }
      cum += h;
    }
    sh_bucket = B;
    sh_rank = PRE - (int)cum;   // 1-indexed rank of T within bucket B
    sh_cnt = 0;
  }
  __syncthreads();
  const int B = sh_bucket, r = sh_rank;
  for (int i = tid; i < NANCH; i += 1024) {
    unsigned long long kv = keys[i];
    if ((int)(kv >> 46) == B) {
      int p = atomicAdd(&sh_cnt, 1);
      if (p < 4096) buf[p] = kv;
    }
  }
  __syncthreads();
  int c = sh_cnt < 4096 ? sh_cnt : 4096;
  for (int i = tid; i < c; i += 1024) {
    unsigned long long kv = buf[i];
    int gt = 0;
    for (int j = 0; j < c; ++j) gt += (buf[j] > kv) ? 1 : 0;
    if (gt == r - 1) *thresh = kv;     // unique keys: exactly one writer
  }
}

__global__ void compact_ge(const unsigned long long* __restrict__ keys,
                           const unsigned long long* __restrict__ thresh,
                           unsigned long long* __restrict__ keys2,
                           unsigned* __restrict__ counter)
{
  int i = blockIdx.x * 256 + threadIdx.x;
  if (i >= NANCH) return;
  unsigned long long kv = keys[i];
  if (kv >= *thresh) keys2[atomicAdd(counter, 1u)] = kv;   // exactly 6000
}

__global__ __launch_bounds__(1024) void sort8192(unsigned long long* __restrict__ keys2)
{
  extern __shared__ unsigned long long s[];
  const int tid = threadIdx.x;
  for (int e = tid; e < 8192; e += 1024) s[e] = (e < PRE) ? keys2[e] : 0ull;
  __syncthreads();
  for (int k = 2; k <= 8192; k <<= 1) {
    for (int j = k >> 1; j >= 1; j >>= 1) {
      for (int e = tid; e < 4096; e += 1024) {
        int lo = ((e & ~(j - 1)) << 1) | (e & (j - 1));
        int hi = lo + j;
        bool dirDesc = ((lo & k) == 0);
        unsigned long long a = s[lo], b = s[hi];
        if (dirDesc ? (a < b) : (a > b)) { s[lo] = b; s[hi] = a; }
      }
      __syncthreads();
    }
  }
  for (int e = tid; e < PRE; e += 1024) keys2[e] = s[e];
}

__global__ void gather_topk(const unsigned long long* __restrict__ keys2,
                            const float* __restrict__ props, float* __restrict__ boxes)
{
  int i = blockIdx.x * 256 + threadIdx.x;
  if (i >= PRE) return;
  unsigned idx = 0x1FFFFu - (unsigned)(keys2[i] & 0x1FFFFull);
  ((float4*)boxes)[i] = ((const float4*)props)[idx];
}

// ---------------- NMS: suppression bit-matrix then blocked scan ----------------
__global__ __launch_bounds__(64) void nms_sup(const float* __restrict__ boxes,
                                              unsigned long long* __restrict__ sup)
{
  const int bi = blockIdx.x, bj = blockIdx.y;
  const int j0 = bj * 64;
  __shared__ float4 cb[64];
  int jt = j0 + threadIdx.x;
  cb[threadIdx.x] = (jt < PRE) ? ((const float4*)boxes)[jt] : make_float4(0,0,0,0);
  __syncthreads();
  int i = bi * 64 + threadIdx.x;
  if (i >= PRE) return;
  float4 b = ((const float4*)boxes)[i];
  double x1 = b.x, y1 = b.y, x2 = b.z, y2 = b.w;
  double area_i = (x2 - x1 + 1.0) * (y2 - y1 + 1.0);
  unsigned long long m = 0ull;
  for (int jj = 0; jj < 64; ++jj) {
    int j = j0 + jj;
    if (j > i && j < PRE) {
      float4 c = cb[jj];
      double xx1 = fmax(x1, (double)c.x), yy1 = fmax(y1, (double)c.y);
      double xx2 = fmin(x2, (double)c.z), yy2 = fmin(y2, (double)c.w);
      double iw = xx2 - xx1 + 1.0, ih = yy2 - yy1 + 1.0;
      if (iw > 0.0 && ih > 0.0) {
        double inter = iw * ih;
        double area_j = ((double)c.z - c.x + 1.0) * ((double)c.w - c.y + 1.0);
        double iou = inter / (area_i + area_j - inter);
        if (iou > 0.7) m |= (1ull << jj);
      }
    }
  }
  sup[(long)i * SUPW + bj] = m;
}

// Blocked greedy scan, exactly equivalent to the reference fori_loop.
__global__ __launch_bounds__(64) void nms_scan(const unsigned long long* __restrict__ sup,
                                               const float* __restrict__ boxes,
                                               float* __restrict__ rois)
{
  __shared__ unsigned long long keep[SUPW];
  __shared__ unsigned long long supl[64];
  __shared__ int kpre[SUPW], spre[SUPW];
  __shared__ int totK;
  __shared__ int pos[POST];
  const int tid = threadIdx.x;
  for (int w = tid; w < SUPW; w += 64) keep[w] = ~0ull;
  __syncthreads();

  for (int b = 0; b < SUPW; ++b) {
    int i = b * 64 + tid;
    supl[tid] = (i < PRE) ? sup[(long)i * SUPW + b] : 0ull;
    __syncthreads();
    unsigned long long kw = keep[b];
    #pragma unroll 8
    for (int k = 0; k < 64; ++k)
      kw &= ~(supl[k] & (0ull - ((kw >> k) & 1ull)));
    if (tid == 0) keep[b] = kw;
    const unsigned long long* colbase = sup + (long)(b * 64) * SUPW;
    for (int wdx = b + 1 + tid; wdx < SUPW; wdx += 64) {
      unsigned long long acc = 0ull;
      #pragma unroll 8
      for (int k = 0; k < 64; ++k)
        acc |= colbase[(long)k * SUPW + wdx] & (0ull - ((kw >> k) & 1ull));
      keep[wdx] &= ~acc;
    }
    __syncthreads();
  }

  if (tid == 0) {
    int kc = 0, sc = 0;
    for (int w = 0; w < SUPW; ++w) {
      unsigned long long valid = (w == SUPW - 1) ? ((1ull << 48) - 1ull) : ~0ull;
      kpre[w] = kc; spre[w] = sc;
      kc += __popcll(keep[w] & valid);
      sc += __popcll(~keep[w] & valid);
    }
    totK = kc;
  }
  __syncthreads();
  const int K = totK;
  for (int w = tid; w < SUPW; w += 64) {
    unsigned long long valid = (w == SUPW - 1) ? ((1ull << 48) - 1ull) : ~0ull;
    unsigned long long kk = keep[w] & valid;
    int r = kpre[w];
    while (kk && r < POST) {
      int k_ = __builtin_ctzll(kk); kk &= kk - 1ull;
      pos[r++] = w * 64 + k_;
    }
    unsigned long long ss = ~keep[w] & valid;
    int r2 = K + spre[w];
    while (ss && r2 < POST) {
      int k_ = __builtin_ctzll(ss); ss &= ss - 1ull;
      pos[r2++] = w * 64 + k_;
    }
  }
  __syncthreads();
  for (int t = tid; t < POST * 4; t += 64)
    rois[t] = boxes[pos[t >> 2] * 4 + (t & 3)];
}

// ---------------- crop_and_resize (14x14 bilinear) + 2x2 maxpool ----------------
__global__ __launch_bounds__(256) void crop_pool(
    const float* __restrict__ feat, const float* __restrict__ rois,
    float* __restrict__ out)
{
  __shared__ int xl[14], xh[14], yl[14], yh[14];
  __shared__ float wx[14], wy[14];
  const int n = blockIdx.x;
  const int tid = threadIdx.x;
  if (tid < 14) {
    float4 r = ((const float4*)rois)[n];
    double fx1 = (double)r.x / 16.0, fy1 = (double)r.y / 16.0;
    double fx2 = (double)r.z / 16.0, fy2 = (double)r.w / 16.0;
    double x1n = fx1 / 119.0, x2n = fx2 / 119.0;
    double y1n = fy1 / 74.0,  y2n = fy2 / 74.0;
    double t = (double)tid / 13.0;
    double xs = (x1n + t * (x2n - x1n)) * 119.0;
    double ys = (y1n + t * (y2n - y1n)) * 74.0;
    double xf = floor(xs), yf = floor(ys);
    wx[tid] = (float)(xs - xf);
    wy[tid] = (float)(ys - yf);
    int xli = (int)fmin(fmax(xf, 0.0), 119.0);
    int yli = (int)fmin(fmax(yf, 0.0), 74.0);
    xl[tid] = xli; xh[tid] = (xli + 1 > 119) ? 119 : xli + 1;
    yl[tid] = yli; yh[tid] = (yli + 1 > 74) ? 74 : yli + 1;
  }
  __syncthreads();
  for (int t = tid; t < 512 * 49; t += 256) {
    int c = t / 49, r = t % 49;
    int py = r / 7, px = r % 7;
    const float* fc = feat + c * NPIX;
    float m = -1e30f;
    #pragma unroll
    for (int sy = 0; sy < 2; ++sy) {
      int iy = py * 2 + sy;
      float wyv = wy[iy];
      int ylo = yl[iy] * WFEAT, yhi = yh[iy] * WFEAT;
      #pragma unroll
      for (int sx = 0; sx < 2; ++sx) {
        int ix = px * 2 + sx;
        float wxv = wx[ix];
        float v00 = fc[ylo + xl[ix]], v01 = fc[ylo + xh[ix]];
        float v10 = fc[yhi + xl[ix]], v11 = fc[yhi + xh[ix]];
        float top = v00 * (1.f - wxv) + v01 * wxv;
        float bot = v10 * (1.f - wxv) + v11 * wxv;
        float val = top * (1.f - wyv) + bot * wyv;
        m = fmaxf(m, val);
      }
    }
    out[(n * 512 + c) * 49 + r] = m;
  }
}

extern "C" void kernel_launch(void* const* d_in, const int* in_sizes, int n_in,
                              void* d_out, int out_size, void* d_ws, size_t ws_size,
                              hipStream_t stream) {
  const float* net    = (const float*)d_in[0];
  const float* rpn_w  = (const float*)d_in[1];
  const float* rpn_b  = (const float*)d_in[2];
  const float* cls_w  = (const float*)d_in[3];
  const float* cls_b  = (const float*)d_in[4];
  const float* bbox_w = (const float*)d_in[5];
  const float* bbox_b = (const float*)d_in[6];
  float* out = (float*)d_out;

  // d_out (30.1 MB): rpn activations use 18.43 MB; the tail hosts the
  // select scratch (hist/counter/thresh/keys2), all dead before crop_pool.
  float* rpn = out;
  unsigned* hist = (unsigned*)(out + 4608000);            // 262144 u32 (1 MB)
  unsigned* counter = hist + HBUCK;                       // 1 u32
  unsigned long long* thresh = (unsigned long long*)(counter + 2); // 8B-aligned
  unsigned long long* keys2 = thresh + 1;                 // 6000 u64

  float* cls   = (float*)d_ws;                    // 162,000 f
  float* bbox  = cls + 162000;                    // 324,000 f
  float* props = bbox + 324000;                   // 324,000 f
  unsigned long long* keys = (unsigned long long*)(props + 324000);  // 81,000 u64
  float* boxes_k = (float*)(keys + 131072);       // 24,000 f
  unsigned long long* sup = (unsigned long long*)(boxes_k + PRE * 4); // 6000*94 u64
  float* rois = (float*)(sup + (size_t)PRE * SUPW); // 1,200 f

  conv3_mfma<<<dim3(75, 2, 8), 256, 0, stream>>>(net, rpn_w, rpn_b, rpn);
  conv1x1<<<71, 256, 0, stream>>>(rpn, cls_w, cls_b, bbox_w, bbox_b, cls, bbox);
  decode_score<<<(NANCH + 255) / 256, 256, 0, stream>>>(cls, bbox, props, keys);

  hipMemsetAsync(hist, 0, (size_t)(HBUCK + 1) * 4, stream);
  hist_hi<<<(NANCH + 255) / 256, 256, 0, stream>>>(keys, hist);
  select_thresh<<<1, 1024, 0, stream>>>(keys, hist, thresh);
  compact_ge<<<(NANCH + 255) / 256, 256, 0, stream>>>(keys, thresh, keys2, counter);
  sort8192<<<1, 1024, 65536, stream>>>(keys2);
  gather_topk<<<(PRE + 255) / 256, 256, 0, stream>>>(keys2, props, boxes_k);

  dim3 gsup(SUPW, SUPW);
  nms_sup<<<gsup, 64, 0, stream>>>(boxes_k, sup);
  nms_scan<<<1, 64, 0, stream>>>(sup, boxes_k, rois);
  crop_pool<<<POST, 256, 0, stream>>>(net, rois, out);
}

// Round 10
// 1994.020 us; speedup vs baseline: 1.2372x; 1.2372x over previous
//
#include <hip/hip_runtime.h>
#include <hip/hip_bf16.h>
#include <math.h>

#define HFEAT 75
#define WFEAT 120
#define NPIX (HFEAT*WFEAT)      // 9000
#define NANCH 81000
#define PRE 6000
#define POST 300
#define SUPW 94                 // ceil(6000/64)
#define HBITS 18
#define HBUCK (1<<HBITS)        // 262144
#define HCHUNK (HBUCK/1024)     // 256

typedef __attribute__((ext_vector_type(4))) float f32x4;
typedef __attribute__((ext_vector_type(8))) short short8;   // 8 bf16 (4 VGPRs)

// 9 base anchors (base_size=16, ratios .5/1/2, scales 8/16/32), precomputed
// exactly per the numpy reference (incl. banker's rounding of 11.5 -> 12).
__constant__ float ANCH[9][4] = {
  {-84.f,-40.f,99.f,55.f},  {-176.f,-88.f,191.f,103.f},{-360.f,-184.f,375.f,199.f},
  {-56.f,-56.f,71.f,71.f},  {-120.f,-120.f,135.f,135.f},{-248.f,-248.f,263.f,263.f},
  {-36.f,-80.f,51.f,95.f},  {-80.f,-168.f,95.f,183.f}, {-168.f,-344.f,183.f,359.f}};

// fp32 -> 3x bf16 split: a ~= s1+s2+s3 (~26 mantissa bits)
__device__ inline void split3(float a, short& s1, short& s2, short& s3) {
  __hip_bfloat16 b1 = __float2bfloat16(a);
  float r = a - __bfloat162float(b1);
  __hip_bfloat16 b2 = __float2bfloat16(r);
  float r2 = r - __bfloat162float(b2);
  __hip_bfloat16 b3 = __float2bfloat16(r2);
  s1 = __builtin_bit_cast(short, b1);
  s2 = __builtin_bit_cast(short, b2);
  s3 = __builtin_bit_cast(short, b3);
}

// ---------------- weight transpose: wt[t][oc][ic] = w[oc][ic][t] ----------------
__global__ void wtrans(const float* __restrict__ w, float* __restrict__ wt) {
  int i = blockIdx.x * 256 + threadIdx.x;           // over 9*512*512 = 2359296
  if (i >= 9 * 512 * 512) return;
  int t = i / (512 * 512);
  int r = i - t * 512 * 512;
  int oc = r >> 9, ic = r & 511;
  wt[i] = w[(size_t)oc * 4608 + ic * 9 + t];        // write coalesced
}

// ---------------- conv 3x3 + bias + relu via bf16x3 MFMA ----------------
// Implicit GEMM: M=64px, N=64oc, K=4608 (16 ic-chunks x 9 taps).
// Weight staging: coalesced from wt + register-pipelined one tap ahead, so
// global latency hides under the previous tap's MFMAs. Numerically identical
// accumulation order to the R9 kernel (absmax must stay 0.015625).
__global__ __launch_bounds__(256) void conv3_mfma(
    const float* __restrict__ in, const float* __restrict__ wt,
    const float* __restrict__ bias, float* __restrict__ out)
{
  __shared__ __align__(16) short in_b[3][3][66][40];  // [split][dy][col][icpad]
  __shared__ __align__(16) short w_b[3][64][40];      // [split][oc][icpad]
  const int tid = threadIdx.x;
  const int lane = tid & 63, wv = tid >> 6;
  const int wm = wv >> 1, wn = wv & 1;
  const int fr = lane & 15, fq = lane >> 4;
  const int y = blockIdx.x;
  const int x0 = blockIdx.y * 56;          // 0 or 56 (overlap recomputed identically)
  const int ocb = blockIdx.z * 64;

  const int oc_w = tid >> 2, icg = (tid & 3) * 8;  // this thread's weight slice

  f32x4 acc[2][2] = {};

  // prologue: preload weights for (c0=0, t=0)
  f32x4 wr0, wr1, wr0n = {}, wr1n = {};
  {
    const float* p = wt + ((size_t)(0 * 512) + ocb + oc_w) * 512 + 0 + icg;
    wr0 = *(const f32x4*)p; wr1 = *(const f32x4*)(p + 4);
  }

  for (int c0 = 0; c0 < 512; c0 += 32) {
    __syncthreads();   // prev chunk's in_b/w_b readers done
    // stage + split input halo: 32ic x 3dy x 66cols
    for (int i = tid; i < 32*3*66; i += 256) {
      int ic = i / 198, r = i - ic * 198;
      int dy = r / 66, cc = r - dy * 66;
      int gy = y + dy - 1, gx = x0 - 1 + cc;
      float v = 0.f;
      if ((unsigned)gy < 75u && (unsigned)gx < 120u)
        v = in[(c0 + ic) * NPIX + gy * WFEAT + gx];
      short s1, s2, s3; split3(v, s1, s2, s3);
      in_b[0][dy][cc][ic] = s1; in_b[1][dy][cc][ic] = s2; in_b[2][dy][cc][ic] = s3;
    }
    for (int t = 0; t < 9; ++t) {
      if (t > 0) __syncthreads();   // prev tap's w_b readers done
      // split this tap's registers into w_b (one b128 write per split)
      {
        float tmp[8] = {wr0.x, wr0.y, wr0.z, wr0.w, wr1.x, wr1.y, wr1.z, wr1.w};
        short8 v1, v2, v3;
        #pragma unroll
        for (int j = 0; j < 8; ++j) {
          short a, b, c; split3(tmp[j], a, b, c);
          v1[j] = a; v2[j] = b; v3[j] = c;
        }
        *(short8*)&w_b[0][oc_w][icg] = v1;
        *(short8*)&w_b[1][oc_w][icg] = v2;
        *(short8*)&w_b[2][oc_w][icg] = v3;
      }
      // issue next tap's weight load (latency hides under this tap's MFMAs)
      {
        int nt = t + 1, nc = c0;
        if (nt == 9) { nt = 0; nc += 32; }
        if (nc < 512) {
          const float* p = wt + ((size_t)(nt * 512) + ocb + oc_w) * 512 + nc + icg;
          wr0n = *(const f32x4*)p; wr1n = *(const f32x4*)(p + 4);
        }
      }
      __syncthreads();              // w_b ready for all waves
      const int dy = t / 3, dx = t - dy * 3;
      short8 af[3][2], bfr[3][2];
      #pragma unroll
      for (int m = 0; m < 2; ++m) {
        int col = wm * 32 + m * 16 + fr + dx;
        #pragma unroll
        for (int s = 0; s < 3; ++s)
          af[s][m] = *(const short8*)&in_b[s][dy][col][fq * 8];
      }
      #pragma unroll
      for (int n = 0; n < 2; ++n) {
        int oc = wn * 32 + n * 16 + fr;
        #pragma unroll
        for (int s = 0; s < 3; ++s)
          bfr[s][n] = *(const short8*)&w_b[s][oc][fq * 8];
      }
      const int pa[6] = {2, 0, 1, 1, 0, 0};
      const int pb[6] = {0, 2, 1, 0, 1, 0};
      #pragma unroll
      for (int p = 0; p < 6; ++p)
        #pragma unroll
        for (int m = 0; m < 2; ++m)
          #pragma unroll
          for (int n = 0; n < 2; ++n)
            acc[m][n] = __builtin_amdgcn_mfma_f32_16x16x32_bf16(
                af[pa[p]][m], bfr[pb[p]][n], acc[m][n], 0, 0, 0);
      wr0 = wr0n; wr1 = wr1n;
    }
  }

  #pragma unroll
  for (int n = 0; n < 2; ++n) {
    int oc = ocb + wn * 32 + n * 16 + fr;
    float bv = bias[oc];
    #pragma unroll
    for (int m = 0; m < 2; ++m) {
      #pragma unroll
      for (int r = 0; r < 4; ++r) {
        int px = wm * 32 + m * 16 + fq * 4 + r;
        float v = acc[m][n][r] + bv;
        out[(size_t)oc * NPIX + y * WFEAT + x0 + px] = v > 0.f ? v : 0.f;
      }
    }
  }
}

// ---------------- 1x1 convs: 18 cls + 36 bbox channels ----------------
__global__ __launch_bounds__(256) void conv1x1(
    const float* __restrict__ rpn,
    const float* __restrict__ wc, const float* __restrict__ bc,
    const float* __restrict__ wb, const float* __restrict__ bb,
    float* __restrict__ cls, float* __restrict__ bbox)
{
  __shared__ float r_s[64][128];
  __shared__ float w_s[54][64];
  const int tid = threadIdx.x;
  const int px0 = blockIdx.x * 128;
  const int px = tid & 127, g = tid >> 7;
  float tot[27];
  #pragma unroll
  for (int j = 0; j < 27; ++j) tot[j] = 0.f;
  for (int ic0 = 0; ic0 < 512; ic0 += 64) {
    __syncthreads();
    for (int i = tid; i < 64*128; i += 256) {
      int ic = i >> 7, p = i & 127;
      int gp = px0 + p;
      r_s[ic][p] = (gp < NPIX) ? rpn[(ic0 + ic) * NPIX + gp] : 0.f;
    }
    for (int i = tid; i < 54*64; i += 256) {
      int c = i >> 6, ic = i & 63;
      w_s[c][ic] = (c < 18) ? wc[c * 512 + ic0 + ic] : wb[(c - 18) * 512 + ic0 + ic];
    }
    __syncthreads();
    float acc[27];
    #pragma unroll
    for (int j = 0; j < 27; ++j) acc[j] = 0.f;
    for (int ic = 0; ic < 64; ++ic) {
      float iv = r_s[ic][px];
      #pragma unroll
      for (int j = 0; j < 27; ++j) acc[j] += iv * w_s[g * 27 + j][ic];
    }
    #pragma unroll
    for (int j = 0; j < 27; ++j) tot[j] += acc[j];
  }
  int gp = px0 + px;
  if (gp < NPIX) {
    for (int j = 0; j < 27; ++j) {
      int c = g * 27 + j;
      if (c < 18) cls[c * NPIX + gp] = tot[j] + bc[c];
      else        bbox[(c - 18) * NPIX + gp] = tot[j] + bb[c - 18];
    }
  }
}

// ---------------- score keys + box decode ----------------
__device__ inline unsigned long long dkey(double d) {
  long long b = __double_as_longlong(d);
  unsigned long long u = (unsigned long long)b;
  return (b < 0) ? ~u : (u | 0x8000000000000000ull);
}

__global__ void decode_score(
    const float* __restrict__ cls, const float* __restrict__ bbox,
    float* __restrict__ props, unsigned long long* __restrict__ keys)
{
  int i = blockIdx.x * 256 + threadIdx.x;
  if (i >= NANCH) return;
  int a = i % 9, p = i / 9;
  int x = p % WFEAT, y = p / WFEAT;
  float c0 = cls[a * NPIX + p], c1 = cls[(9 + a) * NPIX + p];
  double d = (double)c1 - (double)c0;
  unsigned long long s = dkey(d);
  keys[i] = (s & ~0x1FFFFull) | (unsigned long long)(0x1FFFFu - (unsigned)i);

  double ax1 = (double)ANCH[a][0] + 16.0 * x;
  double ay1 = (double)ANCH[a][1] + 16.0 * y;
  double ax2 = (double)ANCH[a][2] + 16.0 * x;
  double ay2 = (double)ANCH[a][3] + 16.0 * y;
  double aw = ax2 - ax1 + 1.0, ah = ay2 - ay1 + 1.0;
  double cx = ax1 + 0.5 * aw,  cy = ay1 + 0.5 * ah;
  double d0 = (double)bbox[(4*a+0) * NPIX + p];
  double d1 = (double)bbox[(4*a+1) * NPIX + p];
  double d2 = (double)bbox[(4*a+2) * NPIX + p];
  double d3 = (double)bbox[(4*a+3) * NPIX + p];
  double pcx = d0 * aw + cx, pcy = d1 * ah + cy;
  double pw = exp(d2) * aw,  ph = exp(d3) * ah;
  double bx1 = pcx - 0.5 * pw, by1 = pcy - 0.5 * ph;
  double bx2 = pcx + 0.5 * pw, by2 = pcy + 0.5 * ph;
  bx1 = fmin(fmax(bx1, 0.0), 1919.0); by1 = fmin(fmax(by1, 0.0), 1199.0);
  bx2 = fmin(fmax(bx2, 0.0), 1919.0); by2 = fmin(fmax(by2, 0.0), 1199.0);
  props[i*4+0] = (float)bx1; props[i*4+1] = (float)by1;
  props[i*4+2] = (float)bx2; props[i*4+3] = (float)by2;
}

// ---------------- exact top-6000 select --------------------------------
__global__ void hist_hi(const unsigned long long* __restrict__ keys,
                        unsigned* __restrict__ hist)
{
  int i = blockIdx.x * 256 + threadIdx.x;
  if (i < NANCH) atomicAdd(&hist[(unsigned)(keys[i] >> 46)], 1u);
}

__global__ __launch_bounds__(1024) void select_thresh(
    const unsigned long long* __restrict__ keys,
    const unsigned* __restrict__ hist, unsigned long long* __restrict__ thresh)
{
  __shared__ unsigned csum[1024];
  __shared__ int sh_bucket, sh_rank, sh_cnt;
  __shared__ unsigned long long buf[4096];
  const int tid = threadIdx.x;
  unsigned s = 0;
  for (int i = 0; i < HCHUNK; ++i) s += hist[tid * HCHUNK + i];
  csum[tid] = s;
  __syncthreads();
  if (tid == 0) {
    unsigned cum = 0; int tc = 0;
    for (int t = 1023; t >= 0; --t) {
      if (cum + csum[t] >= PRE) { tc = t; break; }
      cum += csum[t];
    }
    int B = tc * HCHUNK;
    for (int b0 = HCHUNK - 1; b0 >= 0; --b0) {
      unsigned h = hist[tc * HCHUNK + b0];
      if (cum + h >= PRE) { B = tc * HCHUNK + b0; break; }
      cum += h;
    }
    sh_bucket = B;
    sh_rank = PRE - (int)cum;   // 1-indexed rank of T within bucket B
    sh_cnt = 0;
  }
  __syncthreads();
  const int B = sh_bucket, r = sh_rank;
  for (int i = tid; i < NANCH; i += 1024) {
    unsigned long long kv = keys[i];
    if ((int)(kv >> 46) == B) {
      int p = atomicAdd(&sh_cnt, 1);
      if (p < 4096) buf[p] = kv;
    }
  }
  __syncthreads();
  int c = sh_cnt < 4096 ? sh_cnt : 4096;
  for (int i = tid; i < c; i += 1024) {
    unsigned long long kv = buf[i];
    int gt = 0;
    for (int j = 0; j < c; ++j) gt += (buf[j] > kv) ? 1 : 0;
    if (gt == r - 1) *thresh = kv;     // unique keys: exactly one writer
  }
}

__global__ void compact_ge(const unsigned long long* __restrict__ keys,
                           const unsigned long long* __restrict__ thresh,
                           unsigned long long* __restrict__ keys2,
                           unsigned* __restrict__ counter)
{
  int i = blockIdx.x * 256 + threadIdx.x;
  if (i >= NANCH) return;
  unsigned long long kv = keys[i];
  if (kv >= *thresh) keys2[atomicAdd(counter, 1u)] = kv;   // exactly 6000
}

__global__ __launch_bounds__(1024) void sort8192(unsigned long long* __restrict__ keys2)
{
  extern __shared__ unsigned long long s[];
  const int tid = threadIdx.x;
  for (int e = tid; e < 8192; e += 1024) s[e] = (e < PRE) ? keys2[e] : 0ull;
  __syncthreads();
  for (int k = 2; k <= 8192; k <<= 1) {
    for (int j = k >> 1; j >= 1; j >>= 1) {
      for (int e = tid; e < 4096; e += 1024) {
        int lo = ((e & ~(j - 1)) << 1) | (e & (j - 1));
        int hi = lo + j;
        bool dirDesc = ((lo & k) == 0);
        unsigned long long a = s[lo], b = s[hi];
        if (dirDesc ? (a < b) : (a > b)) { s[lo] = b; s[hi] = a; }
      }
      __syncthreads();
    }
  }
  for (int e = tid; e < PRE; e += 1024) keys2[e] = s[e];
}

__global__ void gather_topk(const unsigned long long* __restrict__ keys2,
                            const float* __restrict__ props, float* __restrict__ boxes)
{
  int i = blockIdx.x * 256 + threadIdx.x;
  if (i >= PRE) return;
  unsigned idx = 0x1FFFFu - (unsigned)(keys2[i] & 0x1FFFFull);
  ((float4*)boxes)[i] = ((const float4*)props)[idx];
}

// ---------------- NMS: suppression bit-matrix then blocked scan ----------------
__global__ __launch_bounds__(64) void nms_sup(const float* __restrict__ boxes,
                                              unsigned long long* __restrict__ sup)
{
  const int bi = blockIdx.x, bj = blockIdx.y;
  const int j0 = bj * 64;
  __shared__ float4 cb[64];
  int jt = j0 + threadIdx.x;
  cb[threadIdx.x] = (jt < PRE) ? ((const float4*)boxes)[jt] : make_float4(0,0,0,0);
  __syncthreads();
  int i = bi * 64 + threadIdx.x;
  if (i >= PRE) return;
  float4 b = ((const float4*)boxes)[i];
  double x1 = b.x, y1 = b.y, x2 = b.z, y2 = b.w;
  double area_i = (x2 - x1 + 1.0) * (y2 - y1 + 1.0);
  unsigned long long m = 0ull;
  for (int jj = 0; jj < 64; ++jj) {
    int j = j0 + jj;
    if (j > i && j < PRE) {
      float4 c = cb[jj];
      double xx1 = fmax(x1, (double)c.x), yy1 = fmax(y1, (double)c.y);
      double xx2 = fmin(x2, (double)c.z), yy2 = fmin(y2, (double)c.w);
      double iw = xx2 - xx1 + 1.0, ih = yy2 - yy1 + 1.0;
      if (iw > 0.0 && ih > 0.0) {
        double inter = iw * ih;
        double area_j = ((double)c.z - c.x + 1.0) * ((double)c.w - c.y + 1.0);
        double iou = inter / (area_i + area_j - inter);
        if (iou > 0.7) m |= (1ull << jj);
      }
    }
  }
  sup[(long)i * SUPW + bj] = m;
}

// Blocked greedy scan, exactly equivalent to the reference fori_loop.
__global__ __launch_bounds__(64) void nms_scan(const unsigned long long* __restrict__ sup,
                                               const float* __restrict__ boxes,
                                               float* __restrict__ rois)
{
  __shared__ unsigned long long keep[SUPW];
  __shared__ unsigned long long supl[64];
  __shared__ int kpre[SUPW], spre[SUPW];
  __shared__ int totK;
  __shared__ int pos[POST];
  const int tid = threadIdx.x;
  for (int w = tid; w < SUPW; w += 64) keep[w] = ~0ull;
  __syncthreads();

  for (int b = 0; b < SUPW; ++b) {
    int i = b * 64 + tid;
    supl[tid] = (i < PRE) ? sup[(long)i * SUPW + b] : 0ull;
    __syncthreads();
    unsigned long long kw = keep[b];
    #pragma unroll 8
    for (int k = 0; k < 64; ++k)
      kw &= ~(supl[k] & (0ull - ((kw >> k) & 1ull)));
    if (tid == 0) keep[b] = kw;
    const unsigned long long* colbase = sup + (long)(b * 64) * SUPW;
    for (int wdx = b + 1 + tid; wdx < SUPW; wdx += 64) {
      unsigned long long acc = 0ull;
      #pragma unroll 8
      for (int k = 0; k < 64; ++k)
        acc |= colbase[(long)k * SUPW + wdx] & (0ull - ((kw >> k) & 1ull));
      keep[wdx] &= ~acc;
    }
    __syncthreads();
  }

  if (tid == 0) {
    int kc = 0, sc = 0;
    for (int w = 0; w < SUPW; ++w) {
      unsigned long long valid = (w == SUPW - 1) ? ((1ull << 48) - 1ull) : ~0ull;
      kpre[w] = kc; spre[w] = sc;
      kc += __popcll(keep[w] & valid);
      sc += __popcll(~keep[w] & valid);
    }
    totK = kc;
  }
  __syncthreads();
  const int K = totK;
  for (int w = tid; w < SUPW; w += 64) {
    unsigned long long valid = (w == SUPW - 1) ? ((1ull << 48) - 1ull) : ~0ull;
    unsigned long long kk = keep[w] & valid;
    int r = kpre[w];
    while (kk && r < POST) {
      int k_ = __builtin_ctzll(kk); kk &= kk - 1ull;
      pos[r++] = w * 64 + k_;
    }
    unsigned long long ss = ~keep[w] & valid;
    int r2 = K + spre[w];
    while (ss && r2 < POST) {
      int k_ = __builtin_ctzll(ss); ss &= ss - 1ull;
      pos[r2++] = w * 64 + k_;
    }
  }
  __syncthreads();
  for (int t = tid; t < POST * 4; t += 64)
    rois[t] = boxes[pos[t >> 2] * 4 + (t & 3)];
}

// ---------------- crop_and_resize (14x14 bilinear) + 2x2 maxpool ----------------
__global__ __launch_bounds__(256) void crop_pool(
    const float* __restrict__ feat, const float* __restrict__ rois,
    float* __restrict__ out)
{
  __shared__ int xl[14], xh[14], yl[14], yh[14];
  __shared__ float wx[14], wy[14];
  const int n = blockIdx.x;
  const int tid = threadIdx.x;
  if (tid < 14) {
    float4 r = ((const float4*)rois)[n];
    double fx1 = (double)r.x / 16.0, fy1 = (double)r.y / 16.0;
    double fx2 = (double)r.z / 16.0, fy2 = (double)r.w / 16.0;
    double x1n = fx1 / 119.0, x2n = fx2 / 119.0;
    double y1n = fy1 / 74.0,  y2n = fy2 / 74.0;
    double t = (double)tid / 13.0;
    double xs = (x1n + t * (x2n - x1n)) * 119.0;
    double ys = (y1n + t * (y2n - y1n)) * 74.0;
    double xf = floor(xs), yf = floor(ys);
    wx[tid] = (float)(xs - xf);
    wy[tid] = (float)(ys - yf);
    int xli = (int)fmin(fmax(xf, 0.0), 119.0);
    int yli = (int)fmin(fmax(yf, 0.0), 74.0);
    xl[tid] = xli; xh[tid] = (xli + 1 > 119) ? 119 : xli + 1;
    yl[tid] = yli; yh[tid] = (yli + 1 > 74) ? 74 : yli + 1;
  }
  __syncthreads();
  for (int t = tid; t < 512 * 49; t += 256) {
    int c = t / 49, r = t % 49;
    int py = r / 7, px = r % 7;
    const float* fc = feat + c * NPIX;
    float m = -1e30f;
    #pragma unroll
    for (int sy = 0; sy < 2; ++sy) {
      int iy = py * 2 + sy;
      float wyv = wy[iy];
      int ylo = yl[iy] * WFEAT, yhi = yh[iy] * WFEAT;
      #pragma unroll
      for (int sx = 0; sx < 2; ++sx) {
        int ix = px * 2 + sx;
        float wxv = wx[ix];
        float v00 = fc[ylo + xl[ix]], v01 = fc[ylo + xh[ix]];
        float v10 = fc[yhi + xl[ix]], v11 = fc[yhi + xh[ix]];
        float top = v00 * (1.f - wxv) + v01 * wxv;
        float bot = v10 * (1.f - wxv) + v11 * wxv;
        float val = top * (1.f - wyv) + bot * wyv;
        m = fmaxf(m, val);
      }
    }
    out[(n * 512 + c) * 49 + r] = m;
  }
}

extern "C" void kernel_launch(void* const* d_in, const int* in_sizes, int n_in,
                              void* d_out, int out_size, void* d_ws, size_t ws_size,
                              hipStream_t stream) {
  const float* net    = (const float*)d_in[0];
  const float* rpn_w  = (const float*)d_in[1];
  const float* rpn_b  = (const float*)d_in[2];
  const float* cls_w  = (const float*)d_in[3];
  const float* cls_b  = (const float*)d_in[4];
  const float* bbox_w = (const float*)d_in[5];
  const float* bbox_b = (const float*)d_in[6];
  float* out = (float*)d_out;

  // d_out (30.1 MB = 7,526,400 f): rpn uses [0, 4,608,000); tail hosts
  // hist/counter/thresh/keys2 and the 9.4 MB transposed-weight buffer wt.
  // All dead before crop_pool's final full-range write.
  float* rpn = out;
  unsigned* hist = (unsigned*)(out + 4608000);            // 262144 u32
  unsigned* counter = hist + HBUCK;                       // 1 u32 (+1 pad)
  unsigned long long* thresh = (unsigned long long*)(counter + 2);
  unsigned long long* keys2 = thresh + 1;                 // 6000 u64
  float* wt = (float*)(keys2 + PRE);                      // 2,359,296 f
  // ends at ~7,241,444 f < 7,526,400 f  ✓

  float* cls   = (float*)d_ws;                    // 162,000 f
  float* bbox  = cls + 162000;                    // 324,000 f
  float* props = bbox + 324000;                   // 324,000 f
  unsigned long long* keys = (unsigned long long*)(props + 324000);  // 81,000 u64
  float* boxes_k = (float*)(keys + 131072);       // 24,000 f
  unsigned long long* sup = (unsigned long long*)(boxes_k + PRE * 4); // 6000*94 u64
  float* rois = (float*)(sup + (size_t)PRE * SUPW); // 1,200 f

  wtrans<<<(9 * 512 * 512 + 255) / 256, 256, 0, stream>>>(rpn_w, wt);
  conv3_mfma<<<dim3(75, 2, 8), 256, 0, stream>>>(net, wt, rpn_b, rpn);
  conv1x1<<<71, 256, 0, stream>>>(rpn, cls_w, cls_b, bbox_w, bbox_b, cls, bbox);
  decode_score<<<(NANCH + 255) / 256, 256, 0, stream>>>(cls, bbox, props, keys);

  hipMemsetAsync(hist, 0, (size_t)(HBUCK + 1) * 4, stream);
  hist_hi<<<(NANCH + 255) / 256, 256, 0, stream>>>(keys, hist);
  select_thresh<<<1, 1024, 0, stream>>>(keys, hist, thresh);
  compact_ge<<<(NANCH + 255) / 256, 256, 0, stream>>>(keys, thresh, keys2, counter);
  sort8192<<<1, 1024, 65536, stream>>>(keys2);
  gather_topk<<<(PRE + 255) / 256, 256, 0, stream>>>(keys2, props, boxes_k);

  dim3 gsup(SUPW, SUPW);
  nms_sup<<<gsup, 64, 0, stream>>>(boxes_k, sup);
  nms_scan<<<1, 64, 0, stream>>>(sup, boxes_k, rois);
  crop_pool<<<POST, 256, 0, stream>>>(net, rois, out);
}

// Round 11
// 1628.065 us; speedup vs baseline: 1.5153x; 1.2248x over previous
//
#include <hip/hip_runtime.h>
#include <hip/hip_bf16.h>
#include <math.h>

#define HFEAT 75
#define WFEAT 120
#define NPIX (HFEAT*WFEAT)      // 9000
#define NANCH 81000
#define PRE 6000
#define POST 300
#define SUPW 94                 // ceil(6000/64)
#define HBITS 18
#define HBUCK (1<<HBITS)        // 262144
#define HCHUNK (HBUCK/1024)     // 256

typedef __attribute__((ext_vector_type(4))) float f32x4;
typedef __attribute__((ext_vector_type(8))) short short8;   // 8 bf16 (4 VGPRs)

// 9 base anchors (base_size=16, ratios .5/1/2, scales 8/16/32), precomputed
// exactly per the numpy reference (incl. banker's rounding of 11.5 -> 12).
__constant__ float ANCH[9][4] = {
  {-84.f,-40.f,99.f,55.f},  {-176.f,-88.f,191.f,103.f},{-360.f,-184.f,375.f,199.f},
  {-56.f,-56.f,71.f,71.f},  {-120.f,-120.f,135.f,135.f},{-248.f,-248.f,263.f,263.f},
  {-36.f,-80.f,51.f,95.f},  {-80.f,-168.f,95.f,183.f}, {-168.f,-344.f,183.f,359.f}};

// fp32 -> 3x bf16 split: a ~= s1+s2+s3 (~26 mantissa bits)
__device__ inline void split3(float a, short& s1, short& s2, short& s3) {
  __hip_bfloat16 b1 = __float2bfloat16(a);
  float r = a - __bfloat162float(b1);
  __hip_bfloat16 b2 = __float2bfloat16(r);
  float r2 = r - __bfloat162float(b2);
  __hip_bfloat16 b3 = __float2bfloat16(r2);
  s1 = __builtin_bit_cast(short, b1);
  s2 = __builtin_bit_cast(short, b2);
  s3 = __builtin_bit_cast(short, b3);
}

// ---------------- weight transpose: wt[t][oc][ic] = w[oc][ic][t] ----------------
__global__ void wtrans(const float* __restrict__ w, float* __restrict__ wt) {
  int i = blockIdx.x * 256 + threadIdx.x;           // over 9*512*512 = 2359296
  if (i >= 9 * 512 * 512) return;
  int t = i / (512 * 512);
  int r = i - t * 512 * 512;
  int oc = r >> 9, ic = r & 511;
  wt[i] = w[(size_t)oc * 4608 + ic * 9 + t];        // write coalesced
}

// ---------------- conv 3x3 + bias + relu via bf16x3 MFMA ----------------
// Implicit GEMM: M=64px, N=64oc, K=4608 (16 ic-chunks x 9 taps).
// B-operands (weights) never touch LDS: each wave loads its 32-oc slice from
// wt into registers (one-tap prefetch) and split3's in-register. Barriers:
// 2 per ic-chunk (32 total vs 288). Input staged as 8-ic strips with one
// ds_write_b128 per split. Accumulation sequence identical to R9/R10
// (absmax must stay exactly 0.015625).
__global__ __launch_bounds__(256) void conv3_mfma(
    const float* __restrict__ in, const float* __restrict__ wt,
    const float* __restrict__ bias, float* __restrict__ out)
{
  __shared__ __align__(16) short in_b[3][3][66][40];  // [split][dy][col][icpad] 46.4KB
  const int tid = threadIdx.x;
  const int lane = tid & 63, wv = tid >> 6;
  const int wm = wv >> 1, wn = wv & 1;
  const int fr = lane & 15, fq = lane >> 4;
  const int y = blockIdx.x;
  const int x0 = blockIdx.y * 56;          // 0 or 56 (overlap recomputed identically)
  const int ocb = blockIdx.z * 64;
  const int ko = fq * 8;

  f32x4 acc[2][2] = {};

  // per-wave weight row pointers (B-fragment: lane fr <-> oc, ko <-> ic)
  const float* wrow0 = wt + (size_t)(ocb + wn * 32 + 0 * 16 + fr) * 512 + ko;
  const float* wrow1 = wt + (size_t)(ocb + wn * 32 + 1 * 16 + fr) * 512 + ko;

  f32x4 bw[2][2], bwN[2][2];
  bw[0][0] = *(const f32x4*)(wrow0);      bw[0][1] = *(const f32x4*)(wrow0 + 4);
  bw[1][0] = *(const f32x4*)(wrow1);      bw[1][1] = *(const f32x4*)(wrow1 + 4);

  for (int c0 = 0; c0 < 512; c0 += 32) {
    __syncthreads();   // previous chunk's in_b readers done
    // stage + split input halo: units (dy, icg, cc) = 3*4*66 = 792
    for (int u = tid; u < 792; u += 256) {
      int dy = u / 264; int r = u - dy * 264;
      int icg = r / 66; int cc = r - icg * 66;
      int gy = y + dy - 1, gx = x0 - 1 + cc;
      bool ok = ((unsigned)gy < 75u) && ((unsigned)gx < 120u);
      const float* ip = in + (size_t)(c0 + icg * 8) * NPIX + gy * WFEAT + gx;
      short8 v1, v2, v3;
      #pragma unroll
      for (int j = 0; j < 8; ++j) {
        float v = ok ? ip[j * NPIX] : 0.f;
        short a, b, c; split3(v, a, b, c);
        v1[j] = a; v2[j] = b; v3[j] = c;
      }
      *(short8*)&in_b[0][dy][cc][icg * 8] = v1;
      *(short8*)&in_b[1][dy][cc][icg * 8] = v2;
      *(short8*)&in_b[2][dy][cc][icg * 8] = v3;
    }
    __syncthreads();   // in_b ready

    for (int t = 0; t < 9; ++t) {
      // split current tap's weights into bf16 fragments (in-register)
      short8 bfrag[3][2];
      #pragma unroll
      for (int n = 0; n < 2; ++n) {
        float tmp[8] = {bw[n][0].x, bw[n][0].y, bw[n][0].z, bw[n][0].w,
                        bw[n][1].x, bw[n][1].y, bw[n][1].z, bw[n][1].w};
        #pragma unroll
        for (int j = 0; j < 8; ++j) {
          short a, b, c; split3(tmp[j], a, b, c);
          bfrag[0][n][j] = a; bfrag[1][n][j] = b; bfrag[2][n][j] = c;
        }
      }
      // prefetch next tap's weights (latency hides under this tap's MFMAs)
      {
        int nt = t + 1, nc = c0;
        if (nt == 9) { nt = 0; nc += 32; }
        if (nc < 512) {
          const float* p0 = wrow0 + (size_t)nt * 262144 + nc;
          const float* p1 = wrow1 + (size_t)nt * 262144 + nc;
          bwN[0][0] = *(const f32x4*)p0; bwN[0][1] = *(const f32x4*)(p0 + 4);
          bwN[1][0] = *(const f32x4*)p1; bwN[1][1] = *(const f32x4*)(p1 + 4);
        }
      }
      const int dy = t / 3, dx = t - dy * 3;
      short8 af[3][2];
      #pragma unroll
      for (int m = 0; m < 2; ++m) {
        int col = wm * 32 + m * 16 + fr + dx;
        #pragma unroll
        for (int s = 0; s < 3; ++s)
          af[s][m] = *(const short8*)&in_b[s][dy][col][ko];
      }
      const int pa[6] = {2, 0, 1, 1, 0, 0};
      const int pb[6] = {0, 2, 1, 0, 1, 0};
      #pragma unroll
      for (int p = 0; p < 6; ++p)
        #pragma unroll
        for (int m = 0; m < 2; ++m)
          #pragma unroll
          for (int n = 0; n < 2; ++n)
            acc[m][n] = __builtin_amdgcn_mfma_f32_16x16x32_bf16(
                af[pa[p]][m], bfrag[pb[p]][n], acc[m][n], 0, 0, 0);
      bw[0][0] = bwN[0][0]; bw[0][1] = bwN[0][1];
      bw[1][0] = bwN[1][0]; bw[1][1] = bwN[1][1];
    }
  }

  #pragma unroll
  for (int n = 0; n < 2; ++n) {
    int oc = ocb + wn * 32 + n * 16 + fr;
    float bv = bias[oc];
    #pragma unroll
    for (int m = 0; m < 2; ++m) {
      #pragma unroll
      for (int r = 0; r < 4; ++r) {
        int px = wm * 32 + m * 16 + fq * 4 + r;
        float v = acc[m][n][r] + bv;
        out[(size_t)oc * NPIX + y * WFEAT + x0 + px] = v > 0.f ? v : 0.f;
      }
    }
  }
}

// ---------------- 1x1 convs: 18 cls + 36 bbox channels ----------------
__global__ __launch_bounds__(256) void conv1x1(
    const float* __restrict__ rpn,
    const float* __restrict__ wc, const float* __restrict__ bc,
    const float* __restrict__ wb, const float* __restrict__ bb,
    float* __restrict__ cls, float* __restrict__ bbox)
{
  __shared__ float r_s[64][128];
  __shared__ float w_s[54][64];
  const int tid = threadIdx.x;
  const int px0 = blockIdx.x * 128;
  const int px = tid & 127, g = tid >> 7;
  float tot[27];
  #pragma unroll
  for (int j = 0; j < 27; ++j) tot[j] = 0.f;
  for (int ic0 = 0; ic0 < 512; ic0 += 64) {
    __syncthreads();
    for (int i = tid; i < 64*128; i += 256) {
      int ic = i >> 7, p = i & 127;
      int gp = px0 + p;
      r_s[ic][p] = (gp < NPIX) ? rpn[(ic0 + ic) * NPIX + gp] : 0.f;
    }
    for (int i = tid; i < 54*64; i += 256) {
      int c = i >> 6, ic = i & 63;
      w_s[c][ic] = (c < 18) ? wc[c * 512 + ic0 + ic] : wb[(c - 18) * 512 + ic0 + ic];
    }
    __syncthreads();
    float acc[27];
    #pragma unroll
    for (int j = 0; j < 27; ++j) acc[j] = 0.f;
    for (int ic = 0; ic < 64; ++ic) {
      float iv = r_s[ic][px];
      #pragma unroll
      for (int j = 0; j < 27; ++j) acc[j] += iv * w_s[g * 27 + j][ic];
    }
    #pragma unroll
    for (int j = 0; j < 27; ++j) tot[j] += acc[j];
  }
  int gp = px0 + px;
  if (gp < NPIX) {
    for (int j = 0; j < 27; ++j) {
      int c = g * 27 + j;
      if (c < 18) cls[c * NPIX + gp] = tot[j] + bc[c];
      else        bbox[(c - 18) * NPIX + gp] = tot[j] + bb[c - 18];
    }
  }
}

// ---------------- score keys + box decode ----------------
__device__ inline unsigned long long dkey(double d) {
  long long b = __double_as_longlong(d);
  unsigned long long u = (unsigned long long)b;
  return (b < 0) ? ~u : (u | 0x8000000000000000ull);
}

__global__ void decode_score(
    const float* __restrict__ cls, const float* __restrict__ bbox,
    float* __restrict__ props, unsigned long long* __restrict__ keys)
{
  int i = blockIdx.x * 256 + threadIdx.x;
  if (i >= NANCH) return;
  int a = i % 9, p = i / 9;
  int x = p % WFEAT, y = p / WFEAT;
  float c0 = cls[a * NPIX + p], c1 = cls[(9 + a) * NPIX + p];
  double d = (double)c1 - (double)c0;
  unsigned long long s = dkey(d);
  keys[i] = (s & ~0x1FFFFull) | (unsigned long long)(0x1FFFFu - (unsigned)i);

  double ax1 = (double)ANCH[a][0] + 16.0 * x;
  double ay1 = (double)ANCH[a][1] + 16.0 * y;
  double ax2 = (double)ANCH[a][2] + 16.0 * x;
  double ay2 = (double)ANCH[a][3] + 16.0 * y;
  double aw = ax2 - ax1 + 1.0, ah = ay2 - ay1 + 1.0;
  double cx = ax1 + 0.5 * aw,  cy = ay1 + 0.5 * ah;
  double d0 = (double)bbox[(4*a+0) * NPIX + p];
  double d1 = (double)bbox[(4*a+1) * NPIX + p];
  double d2 = (double)bbox[(4*a+2) * NPIX + p];
  double d3 = (double)bbox[(4*a+3) * NPIX + p];
  double pcx = d0 * aw + cx, pcy = d1 * ah + cy;
  double pw = exp(d2) * aw,  ph = exp(d3) * ah;
  double bx1 = pcx - 0.5 * pw, by1 = pcy - 0.5 * ph;
  double bx2 = pcx + 0.5 * pw, by2 = pcy + 0.5 * ph;
  bx1 = fmin(fmax(bx1, 0.0), 1919.0); by1 = fmin(fmax(by1, 0.0), 1199.0);
  bx2 = fmin(fmax(bx2, 0.0), 1919.0); by2 = fmin(fmax(by2, 0.0), 1199.0);
  props[i*4+0] = (float)bx1; props[i*4+1] = (float)by1;
  props[i*4+2] = (float)bx2; props[i*4+3] = (float)by2;
}

// ---------------- exact top-6000 select --------------------------------
__global__ void hist_hi(const unsigned long long* __restrict__ keys,
                        unsigned* __restrict__ hist)
{
  int i = blockIdx.x * 256 + threadIdx.x;
  if (i < NANCH) atomicAdd(&hist[(unsigned)(keys[i] >> 46)], 1u);
}

__global__ __launch_bounds__(1024) void select_thresh(
    const unsigned long long* __restrict__ keys,
    const unsigned* __restrict__ hist, unsigned long long* __restrict__ thresh)
{
  __shared__ unsigned csum[1024];
  __shared__ int sh_bucket, sh_rank, sh_cnt;
  __shared__ unsigned long long buf[4096];
  const int tid = threadIdx.x;
  unsigned s = 0;
  for (int i = 0; i < HCHUNK; ++i) s += hist[tid * HCHUNK + i];
  csum[tid] = s;
  __syncthreads();
  if (tid == 0) {
    unsigned cum = 0; int tc = 0;
    for (int t = 1023; t >= 0; --t) {
      if (cum + csum[t] >= PRE) { tc = t; break; }
      cum += csum[t];
    }
    int B = tc * HCHUNK;
    for (int b0 = HCHUNK - 1; b0 >= 0; --b0) {
      unsigned h = hist[tc * HCHUNK + b0];
      if (cum + h >= PRE) { B = tc * HCHUNK + b0; break; }
      cum += h;
    }
    sh_bucket = B;
    sh_rank = PRE - (int)cum;   // 1-indexed rank of T within bucket B
    sh_cnt = 0;
  }
  __syncthreads();
  const int B = sh_bucket, r = sh_rank;
  for (int i = tid; i < NANCH; i += 1024) {
    unsigned long long kv = keys[i];
    if ((int)(kv >> 46) == B) {
      int p = atomicAdd(&sh_cnt, 1);
      if (p < 4096) buf[p] = kv;
    }
  }
  __syncthreads();
  int c = sh_cnt < 4096 ? sh_cnt : 4096;
  for (int i = tid; i < c; i += 1024) {
    unsigned long long kv = buf[i];
    int gt = 0;
    for (int j = 0; j < c; ++j) gt += (buf[j] > kv) ? 1 : 0;
    if (gt == r - 1) *thresh = kv;     // unique keys: exactly one writer
  }
}

__global__ void compact_ge(const unsigned long long* __restrict__ keys,
                           const unsigned long long* __restrict__ thresh,
                           unsigned long long* __restrict__ keys2,
                           unsigned* __restrict__ counter)
{
  int i = blockIdx.x * 256 + threadIdx.x;
  if (i >= NANCH) return;
  unsigned long long kv = keys[i];
  if (kv >= *thresh) keys2[atomicAdd(counter, 1u)] = kv;   // exactly 6000
}

__global__ __launch_bounds__(1024) void sort8192(unsigned long long* __restrict__ keys2)
{
  extern __shared__ unsigned long long s[];
  const int tid = threadIdx.x;
  for (int e = tid; e < 8192; e += 1024) s[e] = (e < PRE) ? keys2[e] : 0ull;
  __syncthreads();
  for (int k = 2; k <= 8192; k <<= 1) {
    for (int j = k >> 1; j >= 1; j >>= 1) {
      for (int e = tid; e < 4096; e += 1024) {
        int lo = ((e & ~(j - 1)) << 1) | (e & (j - 1));
        int hi = lo + j;
        bool dirDesc = ((lo & k) == 0);
        unsigned long long a = s[lo], b = s[hi];
        if (dirDesc ? (a < b) : (a > b)) { s[lo] = b; s[hi] = a; }
      }
      __syncthreads();
    }
  }
  for (int e = tid; e < PRE; e += 1024) keys2[e] = s[e];
}

__global__ void gather_topk(const unsigned long long* __restrict__ keys2,
                            const float* __restrict__ props, float* __restrict__ boxes)
{
  int i = blockIdx.x * 256 + threadIdx.x;
  if (i >= PRE) return;
  unsigned idx = 0x1FFFFu - (unsigned)(keys2[i] & 0x1FFFFull);
  ((float4*)boxes)[i] = ((const float4*)props)[idx];
}

// ---------------- NMS: suppression bit-matrix then blocked scan ----------------
__global__ __launch_bounds__(64) void nms_sup(const float* __restrict__ boxes,
                                              unsigned long long* __restrict__ sup)
{
  const int bi = blockIdx.x, bj = blockIdx.y;
  const int j0 = bj * 64;
  __shared__ float4 cb[64];
  int jt = j0 + threadIdx.x;
  cb[threadIdx.x] = (jt < PRE) ? ((const float4*)boxes)[jt] : make_float4(0,0,0,0);
  __syncthreads();
  int i = bi * 64 + threadIdx.x;
  if (i >= PRE) return;
  float4 b = ((const float4*)boxes)[i];
  double x1 = b.x, y1 = b.y, x2 = b.z, y2 = b.w;
  double area_i = (x2 - x1 + 1.0) * (y2 - y1 + 1.0);
  unsigned long long m = 0ull;
  for (int jj = 0; jj < 64; ++jj) {
    int j = j0 + jj;
    if (j > i && j < PRE) {
      float4 c = cb[jj];
      double xx1 = fmax(x1, (double)c.x), yy1 = fmax(y1, (double)c.y);
      double xx2 = fmin(x2, (double)c.z), yy2 = fmin(y2, (double)c.w);
      double iw = xx2 - xx1 + 1.0, ih = yy2 - yy1 + 1.0;
      if (iw > 0.0 && ih > 0.0) {
        double inter = iw * ih;
        double area_j = ((double)c.z - c.x + 1.0) * ((double)c.w - c.y + 1.0);
        double iou = inter / (area_i + area_j - inter);
        if (iou > 0.7) m |= (1ull << jj);
      }
    }
  }
  sup[(long)i * SUPW + bj] = m;
}

// Blocked greedy scan, exactly equivalent to the reference fori_loop.
__global__ __launch_bounds__(64) void nms_scan(const unsigned long long* __restrict__ sup,
                                               const float* __restrict__ boxes,
                                               float* __restrict__ rois)
{
  __shared__ unsigned long long keep[SUPW];
  __shared__ unsigned long long supl[64];
  __shared__ int kpre[SUPW], spre[SUPW];
  __shared__ int totK;
  __shared__ int pos[POST];
  const int tid = threadIdx.x;
  for (int w = tid; w < SUPW; w += 64) keep[w] = ~0ull;
  __syncthreads();

  for (int b = 0; b < SUPW; ++b) {
    int i = b * 64 + tid;
    supl[tid] = (i < PRE) ? sup[(long)i * SUPW + b] : 0ull;
    __syncthreads();
    unsigned long long kw = keep[b];
    #pragma unroll 8
    for (int k = 0; k < 64; ++k)
      kw &= ~(supl[k] & (0ull - ((kw >> k) & 1ull)));
    if (tid == 0) keep[b] = kw;
    const unsigned long long* colbase = sup + (long)(b * 64) * SUPW;
    for (int wdx = b + 1 + tid; wdx < SUPW; wdx += 64) {
      unsigned long long acc = 0ull;
      #pragma unroll 8
      for (int k = 0; k < 64; ++k)
        acc |= colbase[(long)k * SUPW + wdx] & (0ull - ((kw >> k) & 1ull));
      keep[wdx] &= ~acc;
    }
    __syncthreads();
  }

  if (tid == 0) {
    int kc = 0, sc = 0;
    for (int w = 0; w < SUPW; ++w) {
      unsigned long long valid = (w == SUPW - 1) ? ((1ull << 48) - 1ull) : ~0ull;
      kpre[w] = kc; spre[w] = sc;
      kc += __popcll(keep[w] & valid);
      sc += __popcll(~keep[w] & valid);
    }
    totK = kc;
  }
  __syncthreads();
  const int K = totK;
  for (int w = tid; w < SUPW; w += 64) {
    unsigned long long valid = (w == SUPW - 1) ? ((1ull << 48) - 1ull) : ~0ull;
    unsigned long long kk = keep[w] & valid;
    int r = kpre[w];
    while (kk && r < POST) {
      int k_ = __builtin_ctzll(kk); kk &= kk - 1ull;
      pos[r++] = w * 64 + k_;
    }
    unsigned long long ss = ~keep[w] & valid;
    int r2 = K + spre[w];
    while (ss && r2 < POST) {
      int k_ = __builtin_ctzll(ss); ss &= ss - 1ull;
      pos[r2++] = w * 64 + k_;
    }
  }
  __syncthreads();
  for (int t = tid; t < POST * 4; t += 64)
    rois[t] = boxes[pos[t >> 2] * 4 + (t & 3)];
}

// ---------------- crop_and_resize (14x14 bilinear) + 2x2 maxpool ----------------
__global__ __launch_bounds__(256) void crop_pool(
    const float* __restrict__ feat, const float* __restrict__ rois,
    float* __restrict__ out)
{
  __shared__ int xl[14], xh[14], yl[14], yh[14];
  __shared__ float wx[14], wy[14];
  const int n = blockIdx.x;
  const int tid = threadIdx.x;
  if (tid < 14) {
    float4 r = ((const float4*)rois)[n];
    double fx1 = (double)r.x / 16.0, fy1 = (double)r.y / 16.0;
    double fx2 = (double)r.z / 16.0, fy2 = (double)r.w / 16.0;
    double x1n = fx1 / 119.0, x2n = fx2 / 119.0;
    double y1n = fy1 / 74.0,  y2n = fy2 / 74.0;
    double t = (double)tid / 13.0;
    double xs = (x1n + t * (x2n - x1n)) * 119.0;
    double ys = (y1n + t * (y2n - y1n)) * 74.0;
    double xf = floor(xs), yf = floor(ys);
    wx[tid] = (float)(xs - xf);
    wy[tid] = (float)(ys - yf);
    int xli = (int)fmin(fmax(xf, 0.0), 119.0);
    int yli = (int)fmin(fmax(yf, 0.0), 74.0);
    xl[tid] = xli; xh[tid] = (xli + 1 > 119) ? 119 : xli + 1;
    yl[tid] = yli; yh[tid] = (yli + 1 > 74) ? 74 : yli + 1;
  }
  __syncthreads();
  for (int t = tid; t < 512 * 49; t += 256) {
    int c = t / 49, r = t % 49;
    int py = r / 7, px = r % 7;
    const float* fc = feat + c * NPIX;
    float m = -1e30f;
    #pragma unroll
    for (int sy = 0; sy < 2; ++sy) {
      int iy = py * 2 + sy;
      float wyv = wy[iy];
      int ylo = yl[iy] * WFEAT, yhi = yh[iy] * WFEAT;
      #pragma unroll
      for (int sx = 0; sx < 2; ++sx) {
        int ix = px * 2 + sx;
        float wxv = wx[ix];
        float v00 = fc[ylo + xl[ix]], v01 = fc[ylo + xh[ix]];
        float v10 = fc[yhi + xl[ix]], v11 = fc[yhi + xh[ix]];
        float top = v00 * (1.f - wxv) + v01 * wxv;
        float bot = v10 * (1.f - wxv) + v11 * wxv;
        float val = top * (1.f - wyv) + bot * wyv;
        m = fmaxf(m, val);
      }
    }
    out[(n * 512 + c) * 49 + r] = m;
  }
}

extern "C" void kernel_launch(void* const* d_in, const int* in_sizes, int n_in,
                              void* d_out, int out_size, void* d_ws, size_t ws_size,
                              hipStream_t stream) {
  const float* net    = (const float*)d_in[0];
  const float* rpn_w  = (const float*)d_in[1];
  const float* rpn_b  = (const float*)d_in[2];
  const float* cls_w  = (const float*)d_in[3];
  const float* cls_b  = (const float*)d_in[4];
  const float* bbox_w = (const float*)d_in[5];
  const float* bbox_b = (const float*)d_in[6];
  float* out = (float*)d_out;

  // d_out (30.1 MB = 7,526,400 f): rpn uses [0, 4,608,000); tail hosts
  // hist/counter/thresh/keys2 and the 9.4 MB transposed-weight buffer wt.
  // All dead before crop_pool's final full-range write.
  float* rpn = out;
  unsigned* hist = (unsigned*)(out + 4608000);            // 262144 u32
  unsigned* counter = hist + HBUCK;                       // 1 u32 (+1 pad)
  unsigned long long* thresh = (unsigned long long*)(counter + 2);
  unsigned long long* keys2 = thresh + 1;                 // 6000 u64
  float* wt = (float*)(keys2 + PRE);                      // 2,359,296 f
  // ends at ~7,241,444 f < 7,526,400 f  ✓

  float* cls   = (float*)d_ws;                    // 162,000 f
  float* bbox  = cls + 162000;                    // 324,000 f
  float* props = bbox + 324000;                   // 324,000 f
  unsigned long long* keys = (unsigned long long*)(props + 324000);  // 81,000 u64
  float* boxes_k = (float*)(keys + 131072);       // 24,000 f
  unsigned long long* sup = (unsigned long long*)(boxes_k + PRE * 4); // 6000*94 u64
  float* rois = (float*)(sup + (size_t)PRE * SUPW); // 1,200 f

  wtrans<<<(9 * 512 * 512 + 255) / 256, 256, 0, stream>>>(rpn_w, wt);
  conv3_mfma<<<dim3(75, 2, 8), 256, 0, stream>>>(net, wt, rpn_b, rpn);
  conv1x1<<<71, 256, 0, stream>>>(rpn, cls_w, cls_b, bbox_w, bbox_b, cls, bbox);
  decode_score<<<(NANCH + 255) / 256, 256, 0, stream>>>(cls, bbox, props, keys);

  hipMemsetAsync(hist, 0, (size_t)(HBUCK + 1) * 4, stream);
  hist_hi<<<(NANCH + 255) / 256, 256, 0, stream>>>(keys, hist);
  select_thresh<<<1, 1024, 0, stream>>>(keys, hist, thresh);
  compact_ge<<<(NANCH + 255) / 256, 256, 0, stream>>>(keys, thresh, keys2, counter);
  sort8192<<<1, 1024, 65536, stream>>>(keys2);
  gather_topk<<<(PRE + 255) / 256, 256, 0, stream>>>(keys2, props, boxes_k);

  dim3 gsup(SUPW, SUPW);
  nms_sup<<<gsup, 64, 0, stream>>>(boxes_k, sup);
  nms_scan<<<1, 64, 0, stream>>>(sup, boxes_k, rois);
  crop_pool<<<POST, 256, 0, stream>>>(net, rois, out);
}

// Round 13
// 1497.960 us; speedup vs baseline: 1.6469x; 1.0869x over previous
//
#include <hip/hip_runtime.h>
#include <hip/hip_bf16.h>
#include <math.h>

#define HFEAT 75
#define WFEAT 120
#define NPIX (HFEAT*WFEAT)      // 9000
#define NANCH 81000
#define PRE 6000
#define POST 300
#define SUPW 94                 // ceil(6000/64)
#define HBITS 18
#define HBUCK (1<<HBITS)        // 262144
#define HCHUNK (HBUCK/1024)     // 256

typedef __attribute__((ext_vector_type(4))) float f32x4;
typedef __attribute__((ext_vector_type(8))) short short8;   // 8 bf16 (4 VGPRs)

// 9 base anchors (base_size=16, ratios .5/1/2, scales 8/16/32), precomputed
// exactly per the numpy reference (incl. banker's rounding of 11.5 -> 12).
__constant__ float ANCH[9][4] = {
  {-84.f,-40.f,99.f,55.f},  {-176.f,-88.f,191.f,103.f},{-360.f,-184.f,375.f,199.f},
  {-56.f,-56.f,71.f,71.f},  {-120.f,-120.f,135.f,135.f},{-248.f,-248.f,263.f,263.f},
  {-36.f,-80.f,51.f,95.f},  {-80.f,-168.f,95.f,183.f}, {-168.f,-344.f,183.f,359.f}};

// fp32 -> 3x bf16 split: a ~= s1+s2+s3 (~26 mantissa bits)
__device__ inline void split3(float a, short& s1, short& s2, short& s3) {
  __hip_bfloat16 b1 = __float2bfloat16(a);
  float r = a - __bfloat162float(b1);
  __hip_bfloat16 b2 = __float2bfloat16(r);
  float r2 = r - __bfloat162float(b2);
  __hip_bfloat16 b3 = __float2bfloat16(r2);
  s1 = __builtin_bit_cast(short, b1);
  s2 = __builtin_bit_cast(short, b2);
  s3 = __builtin_bit_cast(short, b3);
}

// ---------------- weight transpose: wt[t][oc][ic] = w[oc][ic][t] ----------------
__global__ void wtrans(const float* __restrict__ w, float* __restrict__ wt) {
  int i = blockIdx.x * 256 + threadIdx.x;           // over 9*512*512 = 2359296
  if (i >= 9 * 512 * 512) return;
  int t = i / (512 * 512);
  int r = i - t * 512 * 512;
  int oc = r >> 9, ic = r & 511;
  wt[i] = w[(size_t)oc * 4608 + ic * 9 + t];        // write coalesced
}

// ---------------- conv 3x3 + bias + relu via bf16x3 MFMA ----------------
// Implicit GEMM: M=64px, N=64oc, K=4608 (16 ic-chunks x 9 taps).
// B-operands (weights) in registers (one-tap prefetch from wt); input staged
// as 8-ic strips, one ds_write_b128 per split. 2 barriers per ic-chunk.
// Accumulation sequence identical to R9-R11 (absmax must stay 0.015625).
__global__ __launch_bounds__(256) void conv3_mfma(
    const float* __restrict__ in, const float* __restrict__ wt,
    const float* __restrict__ bias, float* __restrict__ out)
{
  __shared__ __align__(16) short in_b[3][3][66][40];  // [split][dy][col][icpad] 46.4KB
  const int tid = threadIdx.x;
  const int lane = tid & 63, wv = tid >> 6;
  const int wm = wv >> 1, wn = wv & 1;
  const int fr = lane & 15, fq = lane >> 4;
  const int y = blockIdx.x;
  const int x0 = blockIdx.y * 56;          // 0 or 56 (overlap recomputed identically)
  const int ocb = blockIdx.z * 64;
  const int ko = fq * 8;

  f32x4 acc[2][2] = {};

  const float* wrow0 = wt + (size_t)(ocb + wn * 32 + 0 * 16 + fr) * 512 + ko;
  const float* wrow1 = wt + (size_t)(ocb + wn * 32 + 1 * 16 + fr) * 512 + ko;

  f32x4 bw[2][2], bwN[2][2];
  bw[0][0] = *(const f32x4*)(wrow0);      bw[0][1] = *(const f32x4*)(wrow0 + 4);
  bw[1][0] = *(const f32x4*)(wrow1);      bw[1][1] = *(const f32x4*)(wrow1 + 4);

  for (int c0 = 0; c0 < 512; c0 += 32) {
    __syncthreads();   // previous chunk's in_b readers done
    for (int u = tid; u < 792; u += 256) {
      int dy = u / 264; int r = u - dy * 264;
      int icg = r / 66; int cc = r - icg * 66;
      int gy = y + dy - 1, gx = x0 - 1 + cc;
      bool ok = ((unsigned)gy < 75u) && ((unsigned)gx < 120u);
      const float* ip = in + (size_t)(c0 + icg * 8) * NPIX + gy * WFEAT + gx;
      short8 v1, v2, v3;
      #pragma unroll
      for (int j = 0; j < 8; ++j) {
        float v = ok ? ip[j * NPIX] : 0.f;
        short a, b, c; split3(v, a, b, c);
        v1[j] = a; v2[j] = b; v3[j] = c;
      }
      *(short8*)&in_b[0][dy][cc][icg * 8] = v1;
      *(short8*)&in_b[1][dy][cc][icg * 8] = v2;
      *(short8*)&in_b[2][dy][cc][icg * 8] = v3;
    }
    __syncthreads();   // in_b ready

    for (int t = 0; t < 9; ++t) {
      short8 bfrag[3][2];
      #pragma unroll
      for (int n = 0; n < 2; ++n) {
        float tmp[8] = {bw[n][0].x, bw[n][0].y, bw[n][0].z, bw[n][0].w,
                        bw[n][1].x, bw[n][1].y, bw[n][1].z, bw[n][1].w};
        #pragma unroll
        for (int j = 0; j < 8; ++j) {
          short a, b, c; split3(tmp[j], a, b, c);
          bfrag[0][n][j] = a; bfrag[1][n][j] = b; bfrag[2][n][j] = c;
        }
      }
      {
        int nt = t + 1, nc = c0;
        if (nt == 9) { nt = 0; nc += 32; }
        if (nc < 512) {
          const float* p0 = wrow0 + (size_t)nt * 262144 + nc;
          const float* p1 = wrow1 + (size_t)nt * 262144 + nc;
          bwN[0][0] = *(const f32x4*)p0; bwN[0][1] = *(const f32x4*)(p0 + 4);
          bwN[1][0] = *(const f32x4*)p1; bwN[1][1] = *(const f32x4*)(p1 + 4);
        }
      }
      const int dy = t / 3, dx = t - dy * 3;
      short8 af[3][2];
      #pragma unroll
      for (int m = 0; m < 2; ++m) {
        int col = wm * 32 + m * 16 + fr + dx;
        #pragma unroll
        for (int s = 0; s < 3; ++s)
          af[s][m] = *(const short8*)&in_b[s][dy][col][ko];
      }
      const int pa[6] = {2, 0, 1, 1, 0, 0};
      const int pb[6] = {0, 2, 1, 0, 1, 0};
      #pragma unroll
      for (int p = 0; p < 6; ++p)
        #pragma unroll
        for (int m = 0; m < 2; ++m)
          #pragma unroll
          for (int n = 0; n < 2; ++n)
            acc[m][n] = __builtin_amdgcn_mfma_f32_16x16x32_bf16(
                af[pa[p]][m], bfrag[pb[p]][n], acc[m][n], 0, 0, 0);
      bw[0][0] = bwN[0][0]; bw[0][1] = bwN[0][1];
      bw[1][0] = bwN[1][0]; bw[1][1] = bwN[1][1];
    }
  }

  #pragma unroll
  for (int n = 0; n < 2; ++n) {
    int oc = ocb + wn * 32 + n * 16 + fr;
    float bv = bias[oc];
    #pragma unroll
    for (int m = 0; m < 2; ++m) {
      #pragma unroll
      for (int r = 0; r < 4; ++r) {
        int px = wm * 32 + m * 16 + fq * 4 + r;
        float v = acc[m][n][r] + bv;
        out[(size_t)oc * NPIX + y * WFEAT + x0 + px] = v > 0.f ? v : 0.f;
      }
    }
  }
}

// ---------------- 1x1 convs: 18 cls + 36 bbox channels ----------------
__global__ __launch_bounds__(256) void conv1x1(
    const float* __restrict__ rpn,
    const float* __restrict__ wc, const float* __restrict__ bc,
    const float* __restrict__ wb, const float* __restrict__ bb,
    float* __restrict__ cls, float* __restrict__ bbox)
{
  __shared__ float r_s[64][128];
  __shared__ float w_s[54][64];
  const int tid = threadIdx.x;
  const int px0 = blockIdx.x * 128;
  const int px = tid & 127, g = tid >> 7;
  float tot[27];
  #pragma unroll
  for (int j = 0; j < 27; ++j) tot[j] = 0.f;
  for (int ic0 = 0; ic0 < 512; ic0 += 64) {
    __syncthreads();
    for (int i = tid; i < 64*128; i += 256) {
      int ic = i >> 7, p = i & 127;
      int gp = px0 + p;
      r_s[ic][p] = (gp < NPIX) ? rpn[(ic0 + ic) * NPIX + gp] : 0.f;
    }
    for (int i = tid; i < 54*64; i += 256) {
      int c = i >> 6, ic = i & 63;
      w_s[c][ic] = (c < 18) ? wc[c * 512 + ic0 + ic] : wb[(c - 18) * 512 + ic0 + ic];
    }
    __syncthreads();
    float acc[27];
    #pragma unroll
    for (int j = 0; j < 27; ++j) acc[j] = 0.f;
    for (int ic = 0; ic < 64; ++ic) {
      float iv = r_s[ic][px];
      #pragma unroll
      for (int j = 0; j < 27; ++j) acc[j] += iv * w_s[g * 27 + j][ic];
    }
    #pragma unroll
    for (int j = 0; j < 27; ++j) tot[j] += acc[j];
  }
  int gp = px0 + px;
  if (gp < NPIX) {
    for (int j = 0; j < 27; ++j) {
      int c = g * 27 + j;
      if (c < 18) cls[c * NPIX + gp] = tot[j] + bc[c];
      else        bbox[(c - 18) * NPIX + gp] = tot[j] + bb[c - 18];
    }
  }
}

// ---------------- score keys + box decode ----------------
__device__ inline unsigned long long dkey(double d) {
  long long b = __double_as_longlong(d);
  unsigned long long u = (unsigned long long)b;
  return (b < 0) ? ~u : (u | 0x8000000000000000ull);
}

__global__ void decode_score(
    const float* __restrict__ cls, const float* __restrict__ bbox,
    float* __restrict__ props, unsigned long long* __restrict__ keys)
{
  int i = blockIdx.x * 256 + threadIdx.x;
  if (i >= NANCH) return;
  int a = i % 9, p = i / 9;
  int x = p % WFEAT, y = p / WFEAT;
  float c0 = cls[a * NPIX + p], c1 = cls[(9 + a) * NPIX + p];
  double d = (double)c1 - (double)c0;
  unsigned long long s = dkey(d);
  keys[i] = (s & ~0x1FFFFull) | (unsigned long long)(0x1FFFFu - (unsigned)i);

  double ax1 = (double)ANCH[a][0] + 16.0 * x;
  double ay1 = (double)ANCH[a][1] + 16.0 * y;
  double ax2 = (double)ANCH[a][2] + 16.0 * x;
  double ay2 = (double)ANCH[a][3] + 16.0 * y;
  double aw = ax2 - ax1 + 1.0, ah = ay2 - ay1 + 1.0;
  double cx = ax1 + 0.5 * aw,  cy = ay1 + 0.5 * ah;
  double d0 = (double)bbox[(4*a+0) * NPIX + p];
  double d1 = (double)bbox[(4*a+1) * NPIX + p];
  double d2 = (double)bbox[(4*a+2) * NPIX + p];
  double d3 = (double)bbox[(4*a+3) * NPIX + p];
  double pcx = d0 * aw + cx, pcy = d1 * ah + cy;
  double pw = exp(d2) * aw,  ph = exp(d3) * ah;
  double bx1 = pcx - 0.5 * pw, by1 = pcy - 0.5 * ph;
  double bx2 = pcx + 0.5 * pw, by2 = pcy + 0.5 * ph;
  bx1 = fmin(fmax(bx1, 0.0), 1919.0); by1 = fmin(fmax(by1, 0.0), 1199.0);
  bx2 = fmin(fmax(bx2, 0.0), 1919.0); by2 = fmin(fmax(by2, 0.0), 1199.0);
  props[i*4+0] = (float)bx1; props[i*4+1] = (float)by1;
  props[i*4+2] = (float)bx2; props[i*4+3] = (float)by2;
}

// ---------------- exact top-6000 select --------------------------------
__global__ void hist_hi(const unsigned long long* __restrict__ keys,
                        unsigned* __restrict__ hist)
{
  int i = blockIdx.x * 256 + threadIdx.x;
  if (i < NANCH) atomicAdd(&hist[(unsigned)(keys[i] >> 46)], 1u);
}

__global__ __launch_bounds__(1024) void select_thresh(
    const unsigned long long* __restrict__ keys,
    const unsigned* __restrict__ hist, unsigned long long* __restrict__ thresh)
{
  __shared__ unsigned csum[1024];
  __shared__ int sh_bucket, sh_rank, sh_cnt;
  __shared__ unsigned long long buf[4096];
  const int tid = threadIdx.x;
  unsigned s = 0;
  for (int i = 0; i < HCHUNK; ++i) s += hist[tid * HCHUNK + i];
  csum[tid] = s;
  __syncthreads();
  if (tid == 0) {
    unsigned cum = 0; int tc = 0;
    for (int t = 1023; t >= 0; --t) {
      if (cum + csum[t] >= PRE) { tc = t; break; }
      cum += csum[t];
    }
    int B = tc * HCHUNK;
    for (int b0 = HCHUNK - 1; b0 >= 0; --b0) {
      unsigned h = hist[tc * HCHUNK + b0];
      if (cum + h >= PRE) { B = tc * HCHUNK + b0; break; }
      cum += h;
    }
    sh_bucket = B;
    sh_rank = PRE - (int)cum;   // 1-indexed rank of T within bucket B
    sh_cnt = 0;
  }
  __syncthreads();
  const int B = sh_bucket, r = sh_rank;
  for (int i = tid; i < NANCH; i += 1024) {
    unsigned long long kv = keys[i];
    if ((int)(kv >> 46) == B) {
      int p = atomicAdd(&sh_cnt, 1);
      if (p < 4096) buf[p] = kv;
    }
  }
  __syncthreads();
  int c = sh_cnt < 4096 ? sh_cnt : 4096;
  for (int i = tid; i < c; i += 1024) {
    unsigned long long kv = buf[i];
    int gt = 0;
    for (int j = 0; j < c; ++j) gt += (buf[j] > kv) ? 1 : 0;
    if (gt == r - 1) *thresh = kv;     // unique keys: exactly one writer
  }
}

__global__ void compact_ge(const unsigned long long* __restrict__ keys,
                           const unsigned long long* __restrict__ thresh,
                           unsigned long long* __restrict__ keys2,
                           unsigned* __restrict__ counter)
{
  int i = blockIdx.x * 256 + threadIdx.x;
  if (i >= NANCH) return;
  unsigned long long kv = keys[i];
  if (kv >= *thresh) keys2[atomicAdd(counter, 1u)] = kv;   // exactly 6000
}

__global__ __launch_bounds__(1024) void sort8192(unsigned long long* __restrict__ keys2)
{
  extern __shared__ unsigned long long s[];
  const int tid = threadIdx.x;
  for (int e = tid; e < 8192; e += 1024) s[e] = (e < PRE) ? keys2[e] : 0ull;
  __syncthreads();
  for (int k = 2; k <= 8192; k <<= 1) {
    for (int j = k >> 1; j >= 1; j >>= 1) {
      for (int e = tid; e < 4096; e += 1024) {
        int lo = ((e & ~(j - 1)) << 1) | (e & (j - 1));
        int hi = lo + j;
        bool dirDesc = ((lo & k) == 0);
        unsigned long long a = s[lo], b = s[hi];
        if (dirDesc ? (a < b) : (a > b)) { s[lo] = b; s[hi] = a; }
      }
      __syncthreads();
    }
  }
  for (int e = tid; e < PRE; e += 1024) keys2[e] = s[e];
}

__global__ void gather_topk(const unsigned long long* __restrict__ keys2,
                            const float* __restrict__ props, float* __restrict__ boxes)
{
  int i = blockIdx.x * 256 + threadIdx.x;
  if (i >= PRE) return;
  unsigned idx = 0x1FFFFu - (unsigned)(keys2[i] & 0x1FFFFull);
  ((float4*)boxes)[i] = ((const float4*)props)[idx];
}

// ---------------- NMS: transposed suppression matrix + blocked scan ----------
// supT[wdx][i]: bitmask over word-wdx columns suppressed by row i.
// Written coalesced in i; read contiguously (512B runs) in the scan.
__global__ __launch_bounds__(64) void nms_sup(const float* __restrict__ boxes,
                                              unsigned long long* __restrict__ supT)
{
  const int bi = blockIdx.x, bj = blockIdx.y;
  const int j0 = bj * 64;
  __shared__ float4 cb[64];
  int jt = j0 + threadIdx.x;
  cb[threadIdx.x] = (jt < PRE) ? ((const float4*)boxes)[jt] : make_float4(0,0,0,0);
  __syncthreads();
  int i = bi * 64 + threadIdx.x;
  if (i >= PRE) return;
  float4 b = ((const float4*)boxes)[i];
  double x1 = b.x, y1 = b.y, x2 = b.z, y2 = b.w;
  double area_i = (x2 - x1 + 1.0) * (y2 - y1 + 1.0);
  unsigned long long m = 0ull;
  for (int jj = 0; jj < 64; ++jj) {
    int j = j0 + jj;
    if (j > i && j < PRE) {
      float4 c = cb[jj];
      double xx1 = fmax(x1, (double)c.x), yy1 = fmax(y1, (double)c.y);
      double xx2 = fmin(x2, (double)c.z), yy2 = fmin(y2, (double)c.w);
      double iw = xx2 - xx1 + 1.0, ih = yy2 - yy1 + 1.0;
      if (iw > 0.0 && ih > 0.0) {
        double inter = iw * ih;
        double area_j = ((double)c.z - c.x + 1.0) * ((double)c.w - c.y + 1.0);
        double iou = inter / (area_i + area_j - inter);
        if (iou > 0.7) m |= (1ull << jj);
      }
    }
  }
  supT[(size_t)bj * PRE + i] = m;    // coalesced in i
}

// Blocked greedy scan, exactly equivalent to the reference fori_loop.
// 256 threads: each trailing word gets its own lane; apply reads are 512B
// contiguous runs of supT (4 cache lines vs 64 in the row-major layout).
__global__ __launch_bounds__(256) void nms_scan(const unsigned long long* __restrict__ supT,
                                                const float* __restrict__ boxes,
                                                float* __restrict__ rois)
{
  __shared__ unsigned long long keep[SUPW];
  __shared__ unsigned long long supl[64];
  __shared__ int kpre[SUPW], spre[SUPW];
  __shared__ int totK;
  __shared__ int pos[POST];
  const int tid = threadIdx.x;
  for (int w = tid; w < SUPW; w += 256) keep[w] = ~0ull;
  __syncthreads();

  for (int b = 0; b < SUPW; ++b) {
    // keep[b]'s last write was before the previous barrier -> safe read
    unsigned long long kw = keep[b];
    if (tid < 64) {
      int i = b * 64 + tid;
      supl[tid] = (i < PRE) ? supT[(size_t)b * PRE + i] : 0ull;
    }
    __syncthreads();
    #pragma unroll 8
    for (int k = 0; k < 64; ++k)
      kw &= ~(supl[k] & (0ull - ((kw >> k) & 1ull)));
    if (tid == 0) keep[b] = kw;
    int wdx = b + 1 + tid;
    if (wdx < SUPW) {
      const ulonglong2* p =
          (const ulonglong2*)(supT + (size_t)wdx * PRE + b * 64);
      unsigned long long acc = 0ull;
      #pragma unroll 8
      for (int q = 0; q < 32; ++q) {
        ulonglong2 v = p[q];
        acc |= v.x & (0ull - ((kw >> (2 * q)) & 1ull));
        acc |= v.y & (0ull - ((kw >> (2 * q + 1)) & 1ull));
      }
      keep[wdx] &= ~acc;
    }
    __syncthreads();
  }

  if (tid == 0) {
    int kc = 0, sc = 0;
    for (int w = 0; w < SUPW; ++w) {
      unsigned long long valid = (w == SUPW - 1) ? ((1ull << 48) - 1ull) : ~0ull;
      kpre[w] = kc; spre[w] = sc;
      kc += __popcll(keep[w] & valid);
      sc += __popcll(~keep[w] & valid);
    }
    totK = kc;
  }
  __syncthreads();
  const int K = totK;
  for (int w = tid; w < SUPW; w += 256) {
    unsigned long long valid = (w == SUPW - 1) ? ((1ull << 48) - 1ull) : ~0ull;
    unsigned long long kk = keep[w] & valid;
    int r = kpre[w];
    while (kk && r < POST) {
      int k_ = __builtin_ctzll(kk); kk &= kk - 1ull;
      pos[r++] = w * 64 + k_;
    }
    unsigned long long ss = ~keep[w] & valid;
    int r2 = K + spre[w];
    while (ss && r2 < POST) {
      int k_ = __builtin_ctzll(ss); ss &= ss - 1ull;
      pos[r2++] = w * 64 + k_;
    }
  }
  __syncthreads();
  for (int t = tid; t < POST * 4; t += 256)
    rois[t] = boxes[pos[t >> 2] * 4 + (t & 3)];
}

// ---------------- crop_and_resize (14x14 bilinear) + 2x2 maxpool ----------------
__global__ __launch_bounds__(256) void crop_pool(
    const float* __restrict__ feat, const float* __restrict__ rois,
    float* __restrict__ out)
{
  __shared__ int xl[14], xh[14], yl[14], yh[14];
  __shared__ float wx[14], wy[14];
  const int n = blockIdx.x;
  const int tid = threadIdx.x;
  if (tid < 14) {
    float4 r = ((const float4*)rois)[n];
    double fx1 = (double)r.x / 16.0, fy1 = (double)r.y / 16.0;
    double fx2 = (double)r.z / 16.0, fy2 = (double)r.w / 16.0;
    double x1n = fx1 / 119.0, x2n = fx2 / 119.0;
    double y1n = fy1 / 74.0,  y2n = fy2 / 74.0;
    double t = (double)tid / 13.0;
    double xs = (x1n + t * (x2n - x1n)) * 119.0;
    double ys = (y1n + t * (y2n - y1n)) * 74.0;
    double xf = floor(xs), yf = floor(ys);
    wx[tid] = (float)(xs - xf);
    wy[tid] = (float)(ys - yf);
    int xli = (int)fmin(fmax(xf, 0.0), 119.0);
    int yli = (int)fmin(fmax(yf, 0.0), 74.0);
    xl[tid] = xli; xh[tid] = (xli + 1 > 119) ? 119 : xli + 1;
    yl[tid] = yli; yh[tid] = (yli + 1 > 74) ? 74 : yli + 1;
  }
  __syncthreads();
  for (int t = tid; t < 512 * 49; t += 256) {
    int c = t / 49, r = t % 49;
    int py = r / 7, px = r % 7;
    const float* fc = feat + c * NPIX;
    float m = -1e30f;
    #pragma unroll
    for (int sy = 0; sy < 2; ++sy) {
      int iy = py * 2 + sy;
      float wyv = wy[iy];
      int ylo = yl[iy] * WFEAT, yhi = yh[iy] * WFEAT;
      #pragma unroll
      for (int sx = 0; sx < 2; ++sx) {
        int ix = px * 2 + sx;
        float wxv = wx[ix];
        float v00 = fc[ylo + xl[ix]], v01 = fc[ylo + xh[ix]];
        float v10 = fc[yhi + xl[ix]], v11 = fc[yhi + xh[ix]];
        float top = v00 * (1.f - wxv) + v01 * wxv;
        float bot = v10 * (1.f - wxv) + v11 * wxv;
        float val = top * (1.f - wyv) + bot * wyv;
        m = fmaxf(m, val);
      }
    }
    out[(n * 512 + c) * 49 + r] = m;
  }
}

extern "C" void kernel_launch(void* const* d_in, const int* in_sizes, int n_in,
                              void* d_out, int out_size, void* d_ws, size_t ws_size,
                              hipStream_t stream) {
  const float* net    = (const float*)d_in[0];
  const float* rpn_w  = (const float*)d_in[1];
  const float* rpn_b  = (const float*)d_in[2];
  const float* cls_w  = (const float*)d_in[3];
  const float* cls_b  = (const float*)d_in[4];
  const float* bbox_w = (const float*)d_in[5];
  const float* bbox_b = (const float*)d_in[6];
  float* out = (float*)d_out;

  // d_out (30.1 MB = 7,526,400 f): rpn uses [0, 4,608,000); tail hosts
  // hist/counter/thresh/keys2 and the 9.4 MB transposed-weight buffer wt.
  // All dead before crop_pool's final full-range write.
  float* rpn = out;
  unsigned* hist = (unsigned*)(out + 4608000);            // 262144 u32
  unsigned* counter = hist + HBUCK;                       // 1 u32 (+1 pad)
  unsigned long long* thresh = (unsigned long long*)(counter + 2);
  unsigned long long* keys2 = thresh + 1;                 // 6000 u64
  float* wt = (float*)(keys2 + PRE);                      // 2,359,296 f
  // ends at ~7,241,444 f < 7,526,400 f  ✓

  float* cls   = (float*)d_ws;                    // 162,000 f
  float* bbox  = cls + 162000;                    // 324,000 f
  float* props = bbox + 324000;                   // 324,000 f
  unsigned long long* keys = (unsigned long long*)(props + 324000);  // 81,000 u64
  float* boxes_k = (float*)(keys + 131072);       // 24,000 f
  unsigned long long* supT = (unsigned long long*)(boxes_k + PRE * 4); // 94*6000 u64
  float* rois = (float*)(supT + (size_t)SUPW * PRE); // 1,200 f

  wtrans<<<(9 * 512 * 512 + 255) / 256, 256, 0, stream>>>(rpn_w, wt);
  conv3_mfma<<<dim3(75, 2, 8), 256, 0, stream>>>(net, wt, rpn_b, rpn);
  conv1x1<<<71, 256, 0, stream>>>(rpn, cls_w, cls_b, bbox_w, bbox_b, cls, bbox);
  decode_score<<<(NANCH + 255) / 256, 256, 0, stream>>>(cls, bbox, props, keys);

  hipMemsetAsync(hist, 0, (size_t)(HBUCK + 1) * 4, stream);
  hist_hi<<<(NANCH + 255) / 256, 256, 0, stream>>>(keys, hist);
  select_thresh<<<1, 1024, 0, stream>>>(keys, hist, thresh);
  compact_ge<<<(NANCH + 255) / 256, 256, 0, stream>>>(keys, thresh, keys2, counter);
  sort8192<<<1, 1024, 65536, stream>>>(keys2);
  gather_topk<<<(PRE + 255) / 256, 256, 0, stream>>>(keys2, props, boxes_k);

  dim3 gsup(SUPW, SUPW);
  nms_sup<<<gsup, 64, 0, stream>>>(boxes_k, supT);
  nms_scan<<<1, 256, 0, stream>>>(supT, boxes_k, rois);
  crop_pool<<<POST, 256, 0, stream>>>(net, rois, out);
}